// Round 5
// baseline (1997.707 us; speedup 1.0000x reference)
//
#include <hip/hip_runtime.h>
#include <hip/hip_bf16.h>

#define NTOK   8192
#define DMODEL 384
#define NHEAD  12
#define DHEAD  32
#define NLAYER 6
#define DFF    1536
#define SEQ    512
#define BATCH  16
#define TC     32

typedef __attribute__((ext_vector_type(8))) short short8;
typedef __attribute__((ext_vector_type(4))) float f32x4;

__device__ __forceinline__ float sigmoidf_(float x){ return 1.f/(1.f+expf(-x)); }

__device__ __forceinline__ ushort f2b(float x){
  uint b = __builtin_bit_cast(uint, x);
  uint r = (b + 0x7FFFu + ((b>>16)&1u)) >> 16;
  return (ushort)r;
}
__device__ __forceinline__ uint pk2(float lo, float hi){
  return (uint)f2b(lo) | ((uint)f2b(hi)<<16);
}
// pairwise (lane^1) sum via DPP quad_perm [1,0,3,2]
__device__ __forceinline__ float pair_red(float x){
  int t = __builtin_amdgcn_update_dpp(0, __builtin_bit_cast(int,x), 0xB1, 0xF, 0xF, true);
  return x + __builtin_bit_cast(float, t);
}
__device__ __forceinline__ void gload16(const ushort* g, ushort* l){
  __builtin_amdgcn_global_load_lds((const __attribute__((address_space(1))) void*)g,
                                   (__attribute__((address_space(3))) void*)l, 16, 0, 0);
}

// ---------------- embedding + LN (writes f32 h and bf16 shadow) ----------------
__global__ __launch_bounds__(128) void embed_ln_kernel(
    const int* __restrict__ ids, const float* __restrict__ tok,
    const float* __restrict__ pos, const float* __restrict__ typ,
    const float* __restrict__ g, const float* __restrict__ bvec,
    float* __restrict__ out, ushort* __restrict__ outb)
{
  int n = blockIdx.x;
  int t = n & (SEQ-1);
  int id = ids[n];
  int tid = threadIdx.x;
  float v[3]; float s1=0.f, s2=0.f;
  #pragma unroll
  for (int j=0;j<3;j++){
    int d = tid + j*128;
    float x = tok[(long)id*DMODEL + d] + pos[t*DMODEL + d] + typ[d];
    v[j]=x; s1+=x; s2+=x*x;
  }
  #pragma unroll
  for (int m=1;m<64;m<<=1){ s1 += __shfl_xor(s1,m); s2 += __shfl_xor(s2,m); }
  __shared__ float r1[2], r2[2];
  if ((tid&63)==0){ r1[tid>>6]=s1; r2[tid>>6]=s2; }
  __syncthreads();
  s1 = r1[0]+r1[1]; s2 = r2[0]+r2[1];
  float mean = s1*(1.f/DMODEL);
  float var  = s2*(1.f/DMODEL) - mean*mean;
  float inv  = rsqrtf(var + 1e-12f);
  #pragma unroll
  for (int j=0;j<3;j++){
    int d = tid + j*128;
    float y = (v[j]-mean)*inv*g[d] + bvec[d];
    out[(long)n*DMODEL + d] = y;
    outb[(long)n*DMODEL + d] = f2b(y);
  }
}

// ---------------- residual add + LN (writes f32 + bf16 shadow) ----------------
__global__ __launch_bounds__(128) void add_ln_kernel(
    float* __restrict__ h, const float* __restrict__ res,
    const float* __restrict__ g, const float* __restrict__ bvec,
    ushort* __restrict__ hb)
{
  int n = blockIdx.x;
  int tid = threadIdx.x;
  float v[3]; float s1=0.f, s2=0.f;
  #pragma unroll
  for (int j=0;j<3;j++){
    int d = tid + j*128;
    float x = h[(long)n*DMODEL + d] + res[(long)n*DMODEL + d];
    v[j]=x; s1+=x; s2+=x*x;
  }
  #pragma unroll
  for (int m=1;m<64;m<<=1){ s1 += __shfl_xor(s1,m); s2 += __shfl_xor(s2,m); }
  __shared__ float r1[2], r2[2];
  if ((tid&63)==0){ r1[tid>>6]=s1; r2[tid>>6]=s2; }
  __syncthreads();
  s1 = r1[0]+r1[1]; s2 = r2[0]+r2[1];
  float mean = s1*(1.f/DMODEL);
  float var  = s2*(1.f/DMODEL) - mean*mean;
  float inv  = rsqrtf(var + 1e-12f);
  #pragma unroll
  for (int j=0;j<3;j++){
    int d = tid + j*128;
    float y = (v[j]-mean)*inv*g[d] + bvec[d];
    h[(long)n*DMODEL + d] = y;
    hb[(long)n*DMODEL + d] = f2b(y);
  }
}

// ---------------- per-layer weight transpose+convert into bf16 arena ----------------
// WTA (ushort offsets): QKVG rows[1536][384] @0; O [384][384] @589824;
// W1 [1536][384] @737280; W2 [384][1536] @1327104.
__global__ __launch_bounds__(256) void tcvt_all(
    const float* __restrict__ Wq_l, const float* __restrict__ Wk_l,
    const float* __restrict__ Wv_l, const float* __restrict__ Wg_l,
    const float* __restrict__ Wo_l, const float* __restrict__ W1_l,
    const float* __restrict__ W2_l, ushort* __restrict__ WTA)
{
  __shared__ float tile[32][33];
  int bid = blockIdx.x;
  const float* src; long dstbase; int rowlen, Nd, tk, tn, row0;
  if (bid < 720){
    int seg = bid/144, t = bid%144;
    tk = t%12; tn = t/12;
    src = (seg==0)?Wq_l:(seg==1)?Wk_l:(seg==2)?Wv_l:(seg==3)?Wg_l:Wo_l;
    Nd = 384; rowlen = 384;
    if (seg<4){ dstbase=0; row0=seg*384; }
    else      { dstbase=589824; row0=0; }
  } else if (bid < 1296){
    int t = bid-720; tk=t%12; tn=t/12;
    src=W1_l; Nd=DFF; dstbase=737280; row0=0; rowlen=384;
  } else {
    int t = bid-1296; tk=t%48; tn=t/48;
    src=W2_l; Nd=384; dstbase=1327104; row0=0; rowlen=DFF;
  }
  int k0=tk*32, n0=tn*32;
  int tt=threadIdx.x;
  int r=tt>>3, c4=(tt&7)<<2;
  const float* sp = src + (long)(k0+r)*Nd + n0 + c4;
  float4 f = *(const float4*)sp;
  tile[r][c4+0]=f.x; tile[r][c4+1]=f.y; tile[r][c4+2]=f.z; tile[r][c4+3]=f.w;
  __syncthreads();
  ushort4 o;
  o.x=f2b(tile[c4+0][r]); o.y=f2b(tile[c4+1][r]);
  o.z=f2b(tile[c4+2][r]); o.w=f2b(tile[c4+3][r]);
  *(ushort4*)(WTA + dstbase + (long)(row0+n0+r)*rowlen + k0 + c4) = o;
}

// ---------------- bf16 MFMA GEMM, 128x128 tile, global_load_lds staging ----------------
// A = Xb [M][Kd] bf16, WT [N][Kd] bf16. 4 waves, wave (wm,wn) -> 64x64 sub-tile.
// ACT: 0 none, 1 silu, 2 gelu, 3 sigmoid. OUTBF: store bf16.
template<int ACT, int OUTBF>
__global__ __launch_bounds__(256) void gemm_bf(
    const ushort* __restrict__ Xb, const ushort* __restrict__ WT,
    const float* __restrict__ bias, void* __restrict__ Cv, int Kd, int Nd)
{
  __shared__ ushort A_lds[128*32];
  __shared__ ushort B_lds[128*32];
  int tid = threadIdx.x;
  int bm = blockIdx.x*128, bn = blockIdx.y*128;
  int w = tid>>6, lane = tid&63;
  int wm = w>>1, wn = w&1;
  f32x4 acc[4][4];
  #pragma unroll
  for (int i=0;i<4;i++)
    #pragma unroll
    for (int j=0;j<4;j++) acc[i][j]=(f32x4)(0.f);

  int cl = lane&15, koff = (lane>>4)*8;
  int srow = w*32 + (lane>>2);
  int scol = (lane&3)*8;
  const ushort* gA0 = Xb + (long)(bm+srow)*Kd + scol;
  const ushort* gA1 = gA0 + 16*(long)Kd;
  const ushort* gB0 = WT + (long)(bn+srow)*Kd + scol;
  const ushort* gB1 = gB0 + 16*(long)Kd;
  ushort* lA = A_lds + w*1024;
  ushort* lB = B_lds + w*1024;

  for (int k0=0; k0<Kd; k0+=32){
    gload16(gA0+k0, lA);
    gload16(gA1+k0, lA+512);
    gload16(gB0+k0, lB);
    gload16(gB1+k0, lB+512);
    __syncthreads();
    short8 bf[4];
    #pragma unroll
    for (int ni=0;ni<4;ni++)
      bf[ni] = *(const short8*)&B_lds[(wn*64+ni*16+cl)*32 + koff];
    #pragma unroll
    for (int mi=0;mi<4;mi++){
      short8 af = *(const short8*)&A_lds[(wm*64+mi*16+cl)*32 + koff];
      #pragma unroll
      for (int ni=0;ni<4;ni++)
        acc[mi][ni] = __builtin_amdgcn_mfma_f32_16x16x32_bf16(af, bf[ni], acc[mi][ni], 0,0,0);
    }
    __syncthreads();
  }

  int rb = (lane>>4)*4;
  #pragma unroll
  for (int ni=0; ni<4; ni++){
    int col = bn + wn*64 + ni*16 + cl;
    float bsv = bias ? bias[col] : 0.f;
    #pragma unroll
    for (int mi=0; mi<4; mi++){
      #pragma unroll
      for (int j=0;j<4;j++){
        int row = bm + wm*64 + mi*16 + rb + j;
        float c = acc[mi][ni][j] + bsv;
        if (ACT==1)      c = c*sigmoidf_(c);
        else if (ACT==2) c = 0.5f*c*(1.f+erff(c*0.70710678118f));
        else if (ACT==3) c = sigmoidf_(c);
        if (OUTBF) ((ushort*)Cv)[(long)row*Nd + col] = f2b(c);
        else       ((float*)Cv)[(long)row*Nd + col] = c;
      }
    }
  }
}

// ---------------- fused QKVG GEMM (f32 out, per-segment act/bias) ----------------
// blockIdx.y 0..11 over N=1536; seg = by/3: 0=Q(silu,bq) 1=K(silu,bk) 2=V(none,bv) 3=G(sigmoid)
__global__ __launch_bounds__(256) void gemm_qkvg(
    const ushort* __restrict__ Xb, const ushort* __restrict__ WT,
    const float* __restrict__ bq, const float* __restrict__ bk,
    const float* __restrict__ bv, float* __restrict__ C)
{
  __shared__ ushort A_lds[128*32];
  __shared__ ushort B_lds[128*32];
  int tid = threadIdx.x;
  int bm = blockIdx.x*128, bn = blockIdx.y*128;
  int w = tid>>6, lane = tid&63;
  int wm = w>>1, wn = w&1;
  f32x4 acc[4][4];
  #pragma unroll
  for (int i=0;i<4;i++)
    #pragma unroll
    for (int j=0;j<4;j++) acc[i][j]=(f32x4)(0.f);

  int cl = lane&15, koff = (lane>>4)*8;
  int srow = w*32 + (lane>>2);
  int scol = (lane&3)*8;
  const ushort* gA0 = Xb + (long)(bm+srow)*DMODEL + scol;
  const ushort* gA1 = gA0 + 16*DMODEL;
  const ushort* gB0 = WT + (long)(bn+srow)*DMODEL + scol;
  const ushort* gB1 = gB0 + 16*DMODEL;
  ushort* lA = A_lds + w*1024;
  ushort* lB = B_lds + w*1024;

  for (int k0=0; k0<DMODEL; k0+=32){
    gload16(gA0+k0, lA);
    gload16(gA1+k0, lA+512);
    gload16(gB0+k0, lB);
    gload16(gB1+k0, lB+512);
    __syncthreads();
    short8 bf[4];
    #pragma unroll
    for (int ni=0;ni<4;ni++)
      bf[ni] = *(const short8*)&B_lds[(wn*64+ni*16+cl)*32 + koff];
    #pragma unroll
    for (int mi=0;mi<4;mi++){
      short8 af = *(const short8*)&A_lds[(wm*64+mi*16+cl)*32 + koff];
      #pragma unroll
      for (int ni=0;ni<4;ni++)
        acc[mi][ni] = __builtin_amdgcn_mfma_f32_16x16x32_bf16(af, bf[ni], acc[mi][ni], 0,0,0);
    }
    __syncthreads();
  }

  int seg = blockIdx.y/3;
  const float* bp = (seg==0)?bq:(seg==1)?bk:(seg==2)?bv:nullptr;
  int boff = seg*384;
  int rb = (lane>>4)*4;
  #pragma unroll
  for (int ni=0; ni<4; ni++){
    int col = bn + wn*64 + ni*16 + cl;
    float bsv = bp ? bp[col-boff] : 0.f;
    #pragma unroll
    for (int mi=0; mi<4; mi++){
      #pragma unroll
      for (int j=0;j<4;j++){
        int row = bm + wm*64 + mi*16 + rb + j;
        float c = acc[mi][ni][j] + bsv;
        if (seg<2)       c = c*sigmoidf_(c);
        else if (seg==3) c = sigmoidf_(c);
        C[(long)row*DFF + col] = c;
      }
    }
  }
}

// ---------------- beta = sigmoid(x @ Wb + bb) * mask ----------------
__global__ __launch_bounds__(384) void beta_kernel(
    const float* __restrict__ X, const float* __restrict__ Wb, const float* __restrict__ bb,
    const int* __restrict__ mask, float* __restrict__ Bb)
{
  __shared__ float xs[DMODEL];
  int n = blockIdx.x; int tid = threadIdx.x;
  xs[tid] = X[(long)n*DMODEL + tid];
  __syncthreads();
  int hh = tid >> 5, i = tid & 31;
  float s = 0.f;
  for (int d=i; d<DMODEL; d+=32) s += xs[d]*Wb[d*NHEAD+hh];
  #pragma unroll
  for (int m=1;m<32;m<<=1) s += __shfl_xor(s,m);
  if (i==0) Bb[n*NHEAD+hh] = (float)mask[n] * sigmoidf_(s + bb[hh]);
}

// ---------------- delta-rule scan v5 ----------------
// 192 blocks = (b,h); 128 threads = 2 waves (wave = state). Lane: v = lane>>1, kq = lane&1
// (16 k's per lane in regs). One DPP hop per reduce. Fuses knorm/mix/gate/bf16-out.
__global__ __launch_bounds__(128) void scan5_kernel(
    const float* __restrict__ QKVG, const float* __restrict__ Bb,
    const float* __restrict__ dfl, const float* __restrict__ dsl,
    const float* __restrict__ mixl, ushort* __restrict__ OA)
{
  int bh = blockIdx.x;
  int b = bh / NHEAD, hh = bh - b*NHEAD;
  int tid = threadIdx.x;
  int st = tid>>6, lane = tid&63;
  int v = lane>>1;
  int kq = lane&1;
  float dec = sigmoidf_(st ? dsl[hh] : dfl[hh]);
  float mix = sigmoidf_(mixl[hh]);

  __shared__ float S4[4][TC][33];     // Q,K,V,G chunk
  __shared__ float Ofs[2][TC][34];
  __shared__ float Bc[TC];

  float S[16];
  #pragma unroll
  for (int i=0;i<16;i++) S[i]=0.f;

  long rowbase = (long)b*SEQ;
  for (int c=0;c<SEQ/TC;c++){
    __syncthreads();
    #pragma unroll
    for (int j=0;j<8;j++){
      int flat = tid + 128*j;          // 1024 float4 slots
      int arr = flat>>8, rem = flat&255;
      int r = rem>>3, c4 = (rem&7)<<2;
      long g = (rowbase + c*TC + r)*(long)DFF + arr*384 + hh*32 + c4;
      *(float4*)&S4[arr][r][c4] = *(const float4*)(QKVG + g);
    }
    if (tid < TC) Bc[tid] = Bb[(rowbase + c*TC + tid)*NHEAD + hh];
    __syncthreads();
    if (tid < TC){                     // k row normalization
      float ss=0.f;
      #pragma unroll
      for (int j=0;j<32;j++){ float x=S4[1][tid][j]; ss+=x*x; }
      float inv = 1.f/(sqrtf(ss)+1e-6f);
      #pragma unroll
      for (int j=0;j<32;j++) S4[1][tid][j]*=inv;
    }
    __syncthreads();

    float kr[16], qr[16];
    #pragma unroll
    for (int j=0;j<4;j++){
      *(float4*)&kr[4*j] = *(const float4*)&S4[1][0][kq*16 + 4*j];
      *(float4*)&qr[4*j] = *(const float4*)&S4[0][0][kq*16 + 4*j];
    }
    float vt = S4[2][0][v];
    float bt = Bc[0];

    #pragma unroll 4
    for (int t=0;t<TC;t++){
      int tn = (t+1<TC)?(t+1):t;
      float krn[16], qrn[16];
      #pragma unroll
      for (int j=0;j<4;j++){
        *(float4*)&krn[4*j] = *(const float4*)&S4[1][tn][kq*16 + 4*j];
        *(float4*)&qrn[4*j] = *(const float4*)&S4[0][tn][kq*16 + 4*j];
      }
      float vn = S4[2][tn][v];
      float bn = Bc[tn];

      float p0=0.f,p1=0.f,p2=0.f,p3=0.f;
      #pragma unroll
      for (int j=0;j<4;j++){
        p0 += kr[4*j+0]*S[4*j+0]; p1 += kr[4*j+1]*S[4*j+1];
        p2 += kr[4*j+2]*S[4*j+2]; p3 += kr[4*j+3]*S[4*j+3];
      }
      float p = pair_red((p0+p1)+(p2+p3));
      float err = (vt - p)*bt;
      #pragma unroll
      for (int j=0;j<16;j++) S[j] = dec*S[j] + kr[j]*err;
      float o0=0.f,o1=0.f,o2=0.f,o3=0.f;
      #pragma unroll
      for (int j=0;j<4;j++){
        o0 += qr[4*j+0]*S[4*j+0]; o1 += qr[4*j+1]*S[4*j+1];
        o2 += qr[4*j+2]*S[4*j+2]; o3 += qr[4*j+3]*S[4*j+3];
      }
      float o = pair_red((o0+o1)+(o2+o3));
      if (kq==0) Ofs[st][t][v] = o;

      #pragma unroll
      for (int j=0;j<16;j++){ kr[j]=krn[j]; qr[j]=qrn[j]; }
      vt = vn; bt = bn;
    }
    __syncthreads();
    {                                   // mix + gate + bf16 store (128 thr: 32t x 4 groups)
      int t = tid>>2, v0 = (tid&3)<<3;
      float of[8], os[8], gg[8];
      *(float4*)&of[0] = *(const float4*)&Ofs[0][t][v0];
      *(float4*)&of[4] = *(const float4*)&Ofs[0][t][v0+4];
      *(float4*)&os[0] = *(const float4*)&Ofs[1][t][v0];
      *(float4*)&os[4] = *(const float4*)&Ofs[1][t][v0+4];
      *(float4*)&gg[0] = *(const float4*)&S4[3][t][v0];
      *(float4*)&gg[4] = *(const float4*)&S4[3][t][v0+4];
      uint out4[4];
      #pragma unroll
      for (int j=0;j<4;j++){
        float a  = (mix*of[2*j]   + (1.f-mix)*os[2*j]  )*gg[2*j];
        float b2 = (mix*of[2*j+1] + (1.f-mix)*os[2*j+1])*gg[2*j+1];
        out4[j] = pk2(a,b2);
      }
      *(uint4*)(OA + (rowbase + c*TC + t)*DMODEL + hh*32 + v0) = *(uint4*)&out4[0];
    }
  }
}

// ---------------- masked mean pool + L2 normalize ----------------
__global__ __launch_bounds__(384) void pool_norm_kernel(
    const float* __restrict__ h, const int* __restrict__ mask, float* __restrict__ out)
{
  int b = blockIdx.x; int d = threadIdx.x;
  float s=0.f, ms=0.f;
  for (int t=0;t<SEQ;t++){
    float m = (float)mask[b*SEQ+t];
    s += h[((long)b*SEQ+t)*DMODEL + d]*m;
    ms += m;
  }
  float emb = s / fmaxf(ms, 1e-9f);
  float ss = emb*emb;
  #pragma unroll
  for (int m2=1;m2<64;m2<<=1) ss += __shfl_xor(ss,m2);
  __shared__ float r[6];
  if ((d&63)==0) r[d>>6]=ss;
  __syncthreads();
  ss = r[0]+r[1]+r[2]+r[3]+r[4]+r[5];
  out[b*DMODEL+d] = emb / (sqrtf(ss)+1e-12f);
}

extern "C" void kernel_launch(void* const* d_in, const int* in_sizes, int n_in,
                              void* d_out, int out_size, void* d_ws, size_t ws_size,
                              hipStream_t stream)
{
  const int*   ids   = (const int*)d_in[0];
  const int*   amask = (const int*)d_in[1];
  const float* etok  = (const float*)d_in[2];
  const float* epos  = (const float*)d_in[3];
  const float* etyp  = (const float*)d_in[4];
  const float* elng  = (const float*)d_in[5];
  const float* elnb  = (const float*)d_in[6];
  const float* Wq = (const float*)d_in[7];  const float* bq = (const float*)d_in[8];
  const float* Wk = (const float*)d_in[9];  const float* bk = (const float*)d_in[10];
  const float* Wv = (const float*)d_in[11]; const float* bv = (const float*)d_in[12];
  const float* Wb = (const float*)d_in[13]; const float* bb = (const float*)d_in[14];
  const float* dfl = (const float*)d_in[15];
  const float* dsl = (const float*)d_in[16];
  const float* mixl= (const float*)d_in[17];
  const float* Wg = (const float*)d_in[18];
  const float* Wo = (const float*)d_in[19]; const float* bo = (const float*)d_in[20];
  const float* alng = (const float*)d_in[21]; const float* alnb = (const float*)d_in[22];
  const float* W1 = (const float*)d_in[23]; const float* b1 = (const float*)d_in[24];
  const float* W2 = (const float*)d_in[25]; const float* b2 = (const float*)d_in[26];
  const float* flng = (const float*)d_in[27]; const float* flnb = (const float*)d_in[28];

  float* ws = (float*)d_ws;
  const long TD = (long)NTOK*DMODEL;
  float* h    = ws;                            // [8192][384] f32
  ushort* hbf = (ushort*)(h + TD);             // [8192][384] bf16
  float* QKVG = h + TD + TD/2;                 // [8192][1536] f32
  ushort* OA  = (ushort*)(QKVG + 4*TD);        // [8192][384] bf16
  float* Rb   = QKVG + 4*TD + TD/2;            // attn/ffn output f32
  float* Bb   = Rb + TD;                       // [8192][12]
  ushort* WTA = (ushort*)(Bb + (long)NTOK*NHEAD);
  ushort* F1B = (ushort*)QKVG;                 // FFN mid bf16, aliases dead QKVG

  embed_ln_kernel<<<NTOK,128,0,stream>>>(ids, etok, epos, etyp, elng, elnb, h, hbf);

  for (int l=0;l<NLAYER;l++){
    tcvt_all<<<1872,256,0,stream>>>(
        Wq + (long)l*DMODEL*DMODEL, Wk + (long)l*DMODEL*DMODEL,
        Wv + (long)l*DMODEL*DMODEL, Wg + (long)l*DMODEL*DMODEL,
        Wo + (long)l*DMODEL*DMODEL, W1 + (long)l*DMODEL*DFF,
        W2 + (long)l*DFF*DMODEL, WTA);
    gemm_qkvg<<<dim3(64,12),256,0,stream>>>(hbf, WTA, bq+l*DMODEL, bk+l*DMODEL, bv+l*DMODEL, QKVG);
    beta_kernel<<<NTOK,384,0,stream>>>(h, Wb + (long)l*DMODEL*NHEAD, bb + l*NHEAD, amask, Bb);
    scan5_kernel<<<BATCH*NHEAD,128,0,stream>>>(QKVG, Bb, dfl + l*NHEAD, dsl + l*NHEAD, mixl + l*NHEAD, OA);
    gemm_bf<0,0><<<dim3(64,3),256,0,stream>>>(OA, WTA+589824, bo + l*DMODEL, Rb, DMODEL, DMODEL);
    add_ln_kernel<<<NTOK,128,0,stream>>>(h, Rb, alng + (long)l*DMODEL, alnb + (long)l*DMODEL, hbf);
    gemm_bf<2,1><<<dim3(64,12),256,0,stream>>>(hbf, WTA+737280, b1 + (long)l*DFF, F1B, DMODEL, DFF);
    gemm_bf<0,0><<<dim3(64,3),256,0,stream>>>(F1B, WTA+1327104, b2 + (long)l*DMODEL, Rb, DFF, DMODEL);
    add_ln_kernel<<<NTOK,128,0,stream>>>(h, Rb, flng + (long)l*DMODEL, flnb + (long)l*DMODEL, hbf);
  }

  pool_norm_kernel<<<BATCH,384,0,stream>>>(h, amask, (float*)d_out);
}

// Round 6
// 1545.680 us; speedup vs baseline: 1.2924x; 1.2924x over previous
//
#include <hip/hip_runtime.h>
#include <hip/hip_bf16.h>

#define NTOK   8192
#define DMODEL 384
#define NHEAD  12
#define DHEAD  32
#define NLAYER 6
#define DFF    1536
#define SEQ    512
#define BATCH  16

typedef __attribute__((ext_vector_type(8))) short short8;
typedef __attribute__((ext_vector_type(4))) float f32x4;

__device__ __forceinline__ float sigmoidf_(float x){ return 1.f/(1.f+expf(-x)); }

__device__ __forceinline__ ushort f2b(float x){
  uint b = __builtin_bit_cast(uint, x);
  uint r = (b + 0x7FFFu + ((b>>16)&1u)) >> 16;
  return (ushort)r;
}
__device__ __forceinline__ uint pk2(float lo, float hi){
  return (uint)f2b(lo) | ((uint)f2b(hi)<<16);
}
// 8-lane sum: quad_perm xor1, quad_perm xor2, row_half_mirror (all VALU-rate DPP)
__device__ __forceinline__ float red8(float x){
  int t = __builtin_amdgcn_update_dpp(0, __builtin_bit_cast(int,x), 0xB1, 0xF, 0xF, true);
  x += __builtin_bit_cast(float,t);
  t = __builtin_amdgcn_update_dpp(0, __builtin_bit_cast(int,x), 0x4E, 0xF, 0xF, true);
  x += __builtin_bit_cast(float,t);
  t = __builtin_amdgcn_update_dpp(0, __builtin_bit_cast(int,x), 0x141, 0xF, 0xF, true);
  x += __builtin_bit_cast(float,t);
  return x;
}
__device__ __forceinline__ void gload16(const ushort* g, ushort* l){
  __builtin_amdgcn_global_load_lds((const __attribute__((address_space(1))) void*)g,
                                   (__attribute__((address_space(3))) void*)l, 16, 0, 0);
}

// ---------------- embedding + LN (f32 + bf16 shadow) ----------------
__global__ __launch_bounds__(128) void embed_ln_kernel(
    const int* __restrict__ ids, const float* __restrict__ tok,
    const float* __restrict__ pos, const float* __restrict__ typ,
    const float* __restrict__ g, const float* __restrict__ bvec,
    float* __restrict__ out, ushort* __restrict__ outb)
{
  int n = blockIdx.x;
  int t = n & (SEQ-1);
  int id = ids[n];
  int tid = threadIdx.x;
  float v[3]; float s1=0.f, s2=0.f;
  #pragma unroll
  for (int j=0;j<3;j++){
    int d = tid + j*128;
    float x = tok[(long)id*DMODEL + d] + pos[t*DMODEL + d] + typ[d];
    v[j]=x; s1+=x; s2+=x*x;
  }
  #pragma unroll
  for (int m=1;m<64;m<<=1){ s1 += __shfl_xor(s1,m); s2 += __shfl_xor(s2,m); }
  __shared__ float r1[2], r2[2];
  if ((tid&63)==0){ r1[tid>>6]=s1; r2[tid>>6]=s2; }
  __syncthreads();
  s1 = r1[0]+r1[1]; s2 = r2[0]+r2[1];
  float mean = s1*(1.f/DMODEL);
  float var  = s2*(1.f/DMODEL) - mean*mean;
  float inv  = rsqrtf(var + 1e-12f);
  #pragma unroll
  for (int j=0;j<3;j++){
    int d = tid + j*128;
    float y = (v[j]-mean)*inv*g[d] + bvec[d];
    out[(long)n*DMODEL + d] = y;
    outb[(long)n*DMODEL + d] = f2b(y);
  }
}

// ---------------- residual add + LN (f32 + bf16 shadow) ----------------
__global__ __launch_bounds__(128) void add_ln_kernel(
    float* __restrict__ h, const float* __restrict__ res,
    const float* __restrict__ g, const float* __restrict__ bvec,
    ushort* __restrict__ hb)
{
  int n = blockIdx.x;
  int tid = threadIdx.x;
  float v[3]; float s1=0.f, s2=0.f;
  #pragma unroll
  for (int j=0;j<3;j++){
    int d = tid + j*128;
    float x = h[(long)n*DMODEL + d] + res[(long)n*DMODEL + d];
    v[j]=x; s1+=x; s2+=x*x;
  }
  #pragma unroll
  for (int m=1;m<64;m<<=1){ s1 += __shfl_xor(s1,m); s2 += __shfl_xor(s2,m); }
  __shared__ float r1[2], r2[2];
  if ((tid&63)==0){ r1[tid>>6]=s1; r2[tid>>6]=s2; }
  __syncthreads();
  s1 = r1[0]+r1[1]; s2 = r2[0]+r2[1];
  float mean = s1*(1.f/DMODEL);
  float var  = s2*(1.f/DMODEL) - mean*mean;
  float inv  = rsqrtf(var + 1e-12f);
  #pragma unroll
  for (int j=0;j<3;j++){
    int d = tid + j*128;
    float y = (v[j]-mean)*inv*g[d] + bvec[d];
    h[(long)n*DMODEL + d] = y;
    hb[(long)n*DMODEL + d] = f2b(y);
  }
}

// ---------------- per-layer weight transpose+convert into bf16 arena ----------------
// WTA (ushort offsets): QKVG rows[1536][384] @0; O [384][384] @589824;
// W1 [1536][384] @737280; W2 [384][1536] @1327104.
__global__ __launch_bounds__(256) void tcvt_all(
    const float* __restrict__ Wq_l, const float* __restrict__ Wk_l,
    const float* __restrict__ Wv_l, const float* __restrict__ Wg_l,
    const float* __restrict__ Wo_l, const float* __restrict__ W1_l,
    const float* __restrict__ W2_l, ushort* __restrict__ WTA)
{
  __shared__ float tile[32][33];
  int bid = blockIdx.x;
  const float* src; long dstbase; int rowlen, Nd, tk, tn, row0;
  if (bid < 720){
    int seg = bid/144, t = bid%144;
    tk = t%12; tn = t/12;
    src = (seg==0)?Wq_l:(seg==1)?Wk_l:(seg==2)?Wv_l:(seg==3)?Wg_l:Wo_l;
    Nd = 384; rowlen = 384;
    if (seg<4){ dstbase=0; row0=seg*384; }
    else      { dstbase=589824; row0=0; }
  } else if (bid < 1296){
    int t = bid-720; tk=t%12; tn=t/12;
    src=W1_l; Nd=DFF; dstbase=737280; row0=0; rowlen=384;
  } else {
    int t = bid-1296; tk=t%48; tn=t/48;
    src=W2_l; Nd=384; dstbase=1327104; row0=0; rowlen=DFF;
  }
  int k0=tk*32, n0=tn*32;
  int tt=threadIdx.x;
  int r=tt>>3, c4=(tt&7)<<2;
  const float* sp = src + (long)(k0+r)*Nd + n0 + c4;
  float4 f = *(const float4*)sp;
  tile[r][c4+0]=f.x; tile[r][c4+1]=f.y; tile[r][c4+2]=f.z; tile[r][c4+3]=f.w;
  __syncthreads();
  ushort4 o;
  o.x=f2b(tile[c4+0][r]); o.y=f2b(tile[c4+1][r]);
  o.z=f2b(tile[c4+2][r]); o.w=f2b(tile[c4+3][r]);
  *(ushort4*)(WTA + dstbase + (long)(row0+n0+r)*rowlen + k0 + c4) = o;
}

// ---------------- bf16 MFMA GEMM, 128x128 tile ----------------
template<int ACT, int OUTBF>
__global__ __launch_bounds__(256) void gemm_bf(
    const ushort* __restrict__ Xb, const ushort* __restrict__ WT,
    const float* __restrict__ bias, void* __restrict__ Cv, int Kd, int Nd)
{
  __shared__ ushort A_lds[128*32];
  __shared__ ushort B_lds[128*32];
  int tid = threadIdx.x;
  int bm = blockIdx.x*128, bn = blockIdx.y*128;
  int w = tid>>6, lane = tid&63;
  int wm = w>>1, wn = w&1;
  f32x4 acc[4][4];
  #pragma unroll
  for (int i=0;i<4;i++)
    #pragma unroll
    for (int j=0;j<4;j++) acc[i][j]=(f32x4)(0.f);

  int cl = lane&15, koff = (lane>>4)*8;
  int srow = w*32 + (lane>>2);
  int scol = (lane&3)*8;
  const ushort* gA0 = Xb + (long)(bm+srow)*Kd + scol;
  const ushort* gA1 = gA0 + 16*(long)Kd;
  const ushort* gB0 = WT + (long)(bn+srow)*Kd + scol;
  const ushort* gB1 = gB0 + 16*(long)Kd;
  ushort* lA = A_lds + w*1024;
  ushort* lB = B_lds + w*1024;

  for (int k0=0; k0<Kd; k0+=32){
    gload16(gA0+k0, lA);
    gload16(gA1+k0, lA+512);
    gload16(gB0+k0, lB);
    gload16(gB1+k0, lB+512);
    __syncthreads();
    short8 bf[4];
    #pragma unroll
    for (int ni=0;ni<4;ni++)
      bf[ni] = *(const short8*)&B_lds[(wn*64+ni*16+cl)*32 + koff];
    #pragma unroll
    for (int mi=0;mi<4;mi++){
      short8 af = *(const short8*)&A_lds[(wm*64+mi*16+cl)*32 + koff];
      #pragma unroll
      for (int ni=0;ni<4;ni++)
        acc[mi][ni] = __builtin_amdgcn_mfma_f32_16x16x32_bf16(af, bf[ni], acc[mi][ni], 0,0,0);
    }
    __syncthreads();
  }

  int rb = (lane>>4)*4;
  #pragma unroll
  for (int ni=0; ni<4; ni++){
    int col = bn + wn*64 + ni*16 + cl;
    float bsv = bias ? bias[col] : 0.f;
    #pragma unroll
    for (int mi=0; mi<4; mi++){
      #pragma unroll
      for (int j=0;j<4;j++){
        int row = bm + wm*64 + mi*16 + rb + j;
        float c = acc[mi][ni][j] + bsv;
        if (ACT==1)      c = c*sigmoidf_(c);
        else if (ACT==2) c = 0.5f*c*(1.f+erff(c*0.70710678118f));
        else if (ACT==3) c = sigmoidf_(c);
        if (OUTBF) ((ushort*)Cv)[(long)row*Nd + col] = f2b(c);
        else       ((float*)Cv)[(long)row*Nd + col] = c;
      }
    }
  }
}

// ---------------- bf16 MFMA GEMM, 128x64 tile (for N=384: 384 blocks) ----------------
template<int ACT, int OUTBF>
__global__ __launch_bounds__(256) void gemm_bf2(
    const ushort* __restrict__ Xb, const ushort* __restrict__ WT,
    const float* __restrict__ bias, void* __restrict__ Cv, int Kd, int Nd)
{
  __shared__ ushort A_lds[128*32];
  __shared__ ushort B_lds[64*32];
  int tid = threadIdx.x;
  int bm = blockIdx.x*128, bn = blockIdx.y*64;
  int w = tid>>6, lane = tid&63;
  int wm = w>>1, wn = w&1;
  f32x4 acc[4][2];
  #pragma unroll
  for (int i=0;i<4;i++){ acc[i][0]=(f32x4)(0.f); acc[i][1]=(f32x4)(0.f); }

  int cl = lane&15, koff = (lane>>4)*8;
  int srowA = w*32 + (lane>>2);
  int scol = (lane&3)*8;
  const ushort* gA0 = Xb + (long)(bm+srowA)*Kd + scol;
  const ushort* gA1 = gA0 + 16*(long)Kd;
  int srowB = w*16 + (lane>>2);
  const ushort* gB = WT + (long)(bn+srowB)*Kd + scol;
  ushort* lA = A_lds + w*1024;
  ushort* lB = B_lds + w*512;

  for (int k0=0; k0<Kd; k0+=32){
    gload16(gA0+k0, lA);
    gload16(gA1+k0, lA+512);
    gload16(gB+k0, lB);
    __syncthreads();
    short8 b0 = *(const short8*)&B_lds[(wn*32+cl)*32 + koff];
    short8 b1 = *(const short8*)&B_lds[(wn*32+16+cl)*32 + koff];
    #pragma unroll
    for (int mi=0;mi<4;mi++){
      short8 af = *(const short8*)&A_lds[(wm*64+mi*16+cl)*32 + koff];
      acc[mi][0] = __builtin_amdgcn_mfma_f32_16x16x32_bf16(af, b0, acc[mi][0], 0,0,0);
      acc[mi][1] = __builtin_amdgcn_mfma_f32_16x16x32_bf16(af, b1, acc[mi][1], 0,0,0);
    }
    __syncthreads();
  }

  int rb = (lane>>4)*4;
  #pragma unroll
  for (int ni=0; ni<2; ni++){
    int col = bn + wn*32 + ni*16 + cl;
    float bsv = bias ? bias[col] : 0.f;
    #pragma unroll
    for (int mi=0; mi<4; mi++){
      #pragma unroll
      for (int j=0;j<4;j++){
        int row = bm + wm*64 + mi*16 + rb + j;
        float c = acc[mi][ni][j] + bsv;
        if (ACT==1)      c = c*sigmoidf_(c);
        else if (ACT==2) c = 0.5f*c*(1.f+erff(c*0.70710678118f));
        else if (ACT==3) c = sigmoidf_(c);
        if (OUTBF) ((ushort*)Cv)[(long)row*Nd + col] = f2b(c);
        else       ((float*)Cv)[(long)row*Nd + col] = c;
      }
    }
  }
}

// ---------------- fused QKVG GEMM (f32 out, per-segment act/bias) ----------------
__global__ __launch_bounds__(256) void gemm_qkvg(
    const ushort* __restrict__ Xb, const ushort* __restrict__ WT,
    const float* __restrict__ bq, const float* __restrict__ bk,
    const float* __restrict__ bv, float* __restrict__ C)
{
  __shared__ ushort A_lds[128*32];
  __shared__ ushort B_lds[128*32];
  int tid = threadIdx.x;
  int bm = blockIdx.x*128, bn = blockIdx.y*128;
  int w = tid>>6, lane = tid&63;
  int wm = w>>1, wn = w&1;
  f32x4 acc[4][4];
  #pragma unroll
  for (int i=0;i<4;i++)
    #pragma unroll
    for (int j=0;j<4;j++) acc[i][j]=(f32x4)(0.f);

  int cl = lane&15, koff = (lane>>4)*8;
  int srow = w*32 + (lane>>2);
  int scol = (lane&3)*8;
  const ushort* gA0 = Xb + (long)(bm+srow)*DMODEL + scol;
  const ushort* gA1 = gA0 + 16*DMODEL;
  const ushort* gB0 = WT + (long)(bn+srow)*DMODEL + scol;
  const ushort* gB1 = gB0 + 16*DMODEL;
  ushort* lA = A_lds + w*1024;
  ushort* lB = B_lds + w*1024;

  for (int k0=0; k0<DMODEL; k0+=32){
    gload16(gA0+k0, lA);
    gload16(gA1+k0, lA+512);
    gload16(gB0+k0, lB);
    gload16(gB1+k0, lB+512);
    __syncthreads();
    short8 bf[4];
    #pragma unroll
    for (int ni=0;ni<4;ni++)
      bf[ni] = *(const short8*)&B_lds[(wn*64+ni*16+cl)*32 + koff];
    #pragma unroll
    for (int mi=0;mi<4;mi++){
      short8 af = *(const short8*)&A_lds[(wm*64+mi*16+cl)*32 + koff];
      #pragma unroll
      for (int ni=0;ni<4;ni++)
        acc[mi][ni] = __builtin_amdgcn_mfma_f32_16x16x32_bf16(af, bf[ni], acc[mi][ni], 0,0,0);
    }
    __syncthreads();
  }

  int seg = blockIdx.y/3;
  const float* bp = (seg==0)?bq:(seg==1)?bk:(seg==2)?bv:nullptr;
  int boff = seg*384;
  int rb = (lane>>4)*4;
  #pragma unroll
  for (int ni=0; ni<4; ni++){
    int col = bn + wn*64 + ni*16 + cl;
    float bsv = bp ? bp[col-boff] : 0.f;
    #pragma unroll
    for (int mi=0; mi<4; mi++){
      #pragma unroll
      for (int j=0;j<4;j++){
        int row = bm + wm*64 + mi*16 + rb + j;
        float c = acc[mi][ni][j] + bsv;
        if (seg<2)       c = c*sigmoidf_(c);
        else if (seg==3) c = sigmoidf_(c);
        C[(long)row*DFF + col] = c;
      }
    }
  }
}

// ---------------- k normalization in place on QKVG K-segment ----------------
__global__ __launch_bounds__(384) void knorm2_kernel(float* __restrict__ QKVG)
{
  int n = blockIdx.x; int tid = threadIdx.x;
  long a = (long)n*DFF + 384 + tid;
  float x = QKVG[a];
  float ss = x*x;
  #pragma unroll
  for (int m=1;m<32;m<<=1) ss += __shfl_xor(ss,m);
  QKVG[a] = x / (sqrtf(ss)+1e-6f);
}

// ---------------- beta = sigmoid(x @ Wb + bb) * mask ----------------
__global__ __launch_bounds__(384) void beta_kernel(
    const float* __restrict__ X, const float* __restrict__ Wb, const float* __restrict__ bb,
    const int* __restrict__ mask, float* __restrict__ Bb)
{
  __shared__ float xs[DMODEL];
  int n = blockIdx.x; int tid = threadIdx.x;
  xs[tid] = X[(long)n*DMODEL + tid];
  __syncthreads();
  int hh = tid >> 5, i = tid & 31;
  float s = 0.f;
  for (int d=i; d<DMODEL; d+=32) s += xs[d]*Wb[d*NHEAD+hh];
  #pragma unroll
  for (int m=1;m<32;m<<=1) s += __shfl_xor(s,m);
  if (i==0) Bb[n*NHEAD+hh] = (float)mask[n] * sigmoidf_(s + bb[hh]);
}

// ---------------- delta-rule scan v6 ----------------
// 192 blocks = (b,h); 512 thr = 8 waves: st = w>>2, vq = w&3.
// lane: kq = lane&7 (k = kq*4..+3), v = vq*8 + (lane>>3). S[4] in regs.
// k/q/v/beta loaded global->reg in 8-step groups, double-buffered (A/B named).
// 3-hop DPP reduce. LDS only for per-chunk o exchange; epilogue mixes+gates+bf16.
__device__ __forceinline__ void load_group(
    const float* __restrict__ rp0, const float* __restrict__ bp0,
    int hh, int kq, int v,
    float4 (&kk)[8], float4 (&qq)[8], float (&vv)[8], float (&bb)[8])
{
  #pragma unroll
  for (int i=0;i<8;i++){
    const float* rp = rp0 + (long)i*DFF;
    qq[i] = *(const float4*)(rp + hh*32 + kq*4);
    kk[i] = *(const float4*)(rp + 384 + hh*32 + kq*4);
    vv[i] = rp[768 + hh*32 + v];
    bb[i] = bp0[i*NHEAD];
  }
}
__device__ __forceinline__ void steps8(
    float4 (&kk)[8], float4 (&qq)[8], float (&vv)[8], float (&bb)[8],
    float dec, float (&S)[4], int st, int v, int kq, int tloc,
    float (&Ofs)[2][64][36])
{
  #pragma unroll
  for (int i=0;i<8;i++){
    float4 k4=kk[i], q4=qq[i];
    float pa = k4.x*S[0] + k4.y*S[1];
    float pb = k4.z*S[2] + k4.w*S[3];
    float p = red8(pa+pb);
    float err = (vv[i]-p)*bb[i];
    S[0] = dec*S[0] + k4.x*err;
    S[1] = dec*S[1] + k4.y*err;
    S[2] = dec*S[2] + k4.z*err;
    S[3] = dec*S[3] + k4.w*err;
    float oa = q4.x*S[0] + q4.y*S[1];
    float ob = q4.z*S[2] + q4.w*S[3];
    float o = red8(oa+ob);
    if (kq==0) Ofs[st][tloc+i][v] = o;
  }
}

__global__ __launch_bounds__(512,2) void scan6_kernel(
    const float* __restrict__ QKVG, const float* __restrict__ Bb,
    const float* __restrict__ dfl, const float* __restrict__ dsl,
    const float* __restrict__ mixl, ushort* __restrict__ OA)
{
  __shared__ float Ofs[2][64][36];
  int bh = blockIdx.x;
  int b = bh / NHEAD, hh = bh - b*NHEAD;
  int tid = threadIdx.x;
  int w = tid>>6, lane = tid&63;
  int st = w>>2, vq = w&3;
  int kq = lane&7, v = vq*8 + (lane>>3);
  float dec = sigmoidf_(st ? dsl[hh] : dfl[hh]);
  float mix = sigmoidf_(mixl[hh]);
  long rowbase = (long)b*SEQ;
  const float* rp = QKVG + rowbase*DFF;
  const float* bp = Bb + rowbase*NHEAD + hh;

  float S[4] = {0.f,0.f,0.f,0.f};
  float4 kA[8],qA[8],kB[8],qB[8];
  float  vA[8],bA[8],vB[8],bB[8];

  load_group(rp, bp, hh, kq, v, kA, qA, vA, bA);
  for (int gg=0; gg<64; gg+=2){
    load_group(rp + (long)(gg+1)*8*DFF, bp + (gg+1)*8*NHEAD, hh, kq, v, kB, qB, vB, bB);
    steps8(kA,qA,vA,bA, dec, S, st, v, kq, (gg*8)&63, Ofs);
    if (gg+2<64)
      load_group(rp + (long)(gg+2)*8*DFF, bp + (gg+2)*8*NHEAD, hh, kq, v, kA, qA, vA, bA);
    steps8(kB,qB,vB,bB, dec, S, st, v, kq, (gg*8+8)&63, Ofs);
    if (((gg+1)&7)==7){
      int cidx = (gg+1)>>3;
      __syncthreads();
      int t = tid>>3, v0 = (tid&7)<<2;
      long r = rowbase + cidx*64 + t;
      float4 g4 = *(const float4*)(QKVG + r*DFF + 1152 + hh*32 + v0);
      float4 of = *(const float4*)&Ofs[0][t][v0];
      float4 os = *(const float4*)&Ofs[1][t][v0];
      float a0 = (mix*of.x + (1.f-mix)*os.x)*g4.x;
      float a1 = (mix*of.y + (1.f-mix)*os.y)*g4.y;
      float a2 = (mix*of.z + (1.f-mix)*os.z)*g4.z;
      float a3 = (mix*of.w + (1.f-mix)*os.w)*g4.w;
      uint2 o2; o2.x = pk2(a0,a1); o2.y = pk2(a2,a3);
      *(uint2*)(OA + r*DMODEL + hh*32 + v0) = o2;
      __syncthreads();
    }
  }
}

// ---------------- masked mean pool + L2 normalize ----------------
__global__ __launch_bounds__(384) void pool_norm_kernel(
    const float* __restrict__ h, const int* __restrict__ mask, float* __restrict__ out)
{
  int b = blockIdx.x; int d = threadIdx.x;
  float s=0.f, ms=0.f;
  for (int t=0;t<SEQ;t++){
    float m = (float)mask[b*SEQ+t];
    s += h[((long)b*SEQ+t)*DMODEL + d]*m;
    ms += m;
  }
  float emb = s / fmaxf(ms, 1e-9f);
  float ss = emb*emb;
  #pragma unroll
  for (int m2=1;m2<64;m2<<=1) ss += __shfl_xor(ss,m2);
  __shared__ float r[6];
  if ((d&63)==0) r[d>>6]=ss;
  __syncthreads();
  ss = r[0]+r[1]+r[2]+r[3]+r[4]+r[5];
  out[b*DMODEL+d] = emb / (sqrtf(ss)+1e-12f);
}

extern "C" void kernel_launch(void* const* d_in, const int* in_sizes, int n_in,
                              void* d_out, int out_size, void* d_ws, size_t ws_size,
                              hipStream_t stream)
{
  const int*   ids   = (const int*)d_in[0];
  const int*   amask = (const int*)d_in[1];
  const float* etok  = (const float*)d_in[2];
  const float* epos  = (const float*)d_in[3];
  const float* etyp  = (const float*)d_in[4];
  const float* elng  = (const float*)d_in[5];
  const float* elnb  = (const float*)d_in[6];
  const float* Wq = (const float*)d_in[7];  const float* bq = (const float*)d_in[8];
  const float* Wk = (const float*)d_in[9];  const float* bk = (const float*)d_in[10];
  const float* Wv = (const float*)d_in[11]; const float* bv = (const float*)d_in[12];
  const float* Wb = (const float*)d_in[13]; const float* bb = (const float*)d_in[14];
  const float* dfl = (const float*)d_in[15];
  const float* dsl = (const float*)d_in[16];
  const float* mixl= (const float*)d_in[17];
  const float* Wg = (const float*)d_in[18];
  const float* Wo = (const float*)d_in[19]; const float* bo = (const float*)d_in[20];
  const float* alng = (const float*)d_in[21]; const float* alnb = (const float*)d_in[22];
  const float* W1 = (const float*)d_in[23]; const float* b1 = (const float*)d_in[24];
  const float* W2 = (const float*)d_in[25]; const float* b2 = (const float*)d_in[26];
  const float* flng = (const float*)d_in[27]; const float* flnb = (const float*)d_in[28];

  float* ws = (float*)d_ws;
  const long TD = (long)NTOK*DMODEL;
  float* h    = ws;                            // [8192][384] f32
  ushort* hbf = (ushort*)(h + TD);             // [8192][384] bf16
  float* QKVG = h + TD + TD/2;                 // [8192][1536] f32
  ushort* OA  = (ushort*)(QKVG + 4*TD);        // [8192][384] bf16
  float* Rb   = QKVG + 4*TD + TD/2;            // attn/ffn output f32
  float* Bb   = Rb + TD;                       // [8192][12]
  ushort* WTA = (ushort*)(Bb + (long)NTOK*NHEAD);
  ushort* F1B = (ushort*)QKVG;                 // FFN mid bf16, aliases dead QKVG

  embed_ln_kernel<<<NTOK,128,0,stream>>>(ids, etok, epos, etyp, elng, elnb, h, hbf);

  for (int l=0;l<NLAYER;l++){
    tcvt_all<<<1872,256,0,stream>>>(
        Wq + (long)l*DMODEL*DMODEL, Wk + (long)l*DMODEL*DMODEL,
        Wv + (long)l*DMODEL*DMODEL, Wg + (long)l*DMODEL*DMODEL,
        Wo + (long)l*DMODEL*DMODEL, W1 + (long)l*DMODEL*DFF,
        W2 + (long)l*DFF*DMODEL, WTA);
    gemm_qkvg<<<dim3(64,12),256,0,stream>>>(hbf, WTA, bq+l*DMODEL, bk+l*DMODEL, bv+l*DMODEL, QKVG);
    knorm2_kernel<<<NTOK,384,0,stream>>>(QKVG);
    beta_kernel<<<NTOK,384,0,stream>>>(h, Wb + (long)l*DMODEL*NHEAD, bb + l*NHEAD, amask, Bb);
    scan6_kernel<<<BATCH*NHEAD,512,0,stream>>>(QKVG, Bb, dfl + l*NHEAD, dsl + l*NHEAD, mixl + l*NHEAD, OA);
    gemm_bf2<0,0><<<dim3(64,6),256,0,stream>>>(OA, WTA+589824, bo + l*DMODEL, Rb, DMODEL, DMODEL);
    add_ln_kernel<<<NTOK,128,0,stream>>>(h, Rb, alng + (long)l*DMODEL, alnb + (long)l*DMODEL, hbf);
    gemm_bf<2,1><<<dim3(64,12),256,0,stream>>>(hbf, WTA+737280, b1 + (long)l*DFF, F1B, DMODEL, DFF);
    gemm_bf2<0,0><<<dim3(64,6),256,0,stream>>>(F1B, WTA+1327104, b2 + (long)l*DMODEL, Rb, DFF, DMODEL);
    add_ln_kernel<<<NTOK,128,0,stream>>>(h, Rb, flng + (long)l*DMODEL, flnb + (long)l*DMODEL, hbf);
  }

  pool_norm_kernel<<<BATCH,384,0,stream>>>(h, amask, (float*)d_out);
}

// Round 7
// 1525.014 us; speedup vs baseline: 1.3100x; 1.0136x over previous
//
#include <hip/hip_runtime.h>
#include <hip/hip_bf16.h>

#define NTOK   8192
#define DMODEL 384
#define NHEAD  12
#define DHEAD  32
#define NLAYER 6
#define DFF    1536
#define SEQ    512
#define BATCH  16

typedef __attribute__((ext_vector_type(8))) short short8;
typedef __attribute__((ext_vector_type(4))) float f32x4;

__device__ __forceinline__ float sigmoidf_(float x){ return 1.f/(1.f+expf(-x)); }

__device__ __forceinline__ ushort f2b(float x){
  uint b = __builtin_bit_cast(uint, x);
  uint r = (b + 0x7FFFu + ((b>>16)&1u)) >> 16;
  return (ushort)r;
}
__device__ __forceinline__ uint pk2(float lo, float hi){
  return (uint)f2b(lo) | ((uint)f2b(hi)<<16);
}
// 8-lane sum: quad_perm xor1, quad_perm xor2, row_half_mirror (all VALU-rate DPP)
__device__ __forceinline__ float red8(float x){
  int t = __builtin_amdgcn_update_dpp(0, __builtin_bit_cast(int,x), 0xB1, 0xF, 0xF, true);
  x += __builtin_bit_cast(float,t);
  t = __builtin_amdgcn_update_dpp(0, __builtin_bit_cast(int,x), 0x4E, 0xF, 0xF, true);
  x += __builtin_bit_cast(float,t);
  t = __builtin_amdgcn_update_dpp(0, __builtin_bit_cast(int,x), 0x141, 0xF, 0xF, true);
  x += __builtin_bit_cast(float,t);
  return x;
}
__device__ __forceinline__ void gload16(const ushort* g, ushort* l){
  __builtin_amdgcn_global_load_lds((const __attribute__((address_space(1))) void*)g,
                                   (__attribute__((address_space(3))) void*)l, 16, 0, 0);
}

// ---------------- embedding + LN (f32 + bf16 shadow) ----------------
__global__ __launch_bounds__(128) void embed_ln_kernel(
    const int* __restrict__ ids, const float* __restrict__ tok,
    const float* __restrict__ pos, const float* __restrict__ typ,
    const float* __restrict__ g, const float* __restrict__ bvec,
    float* __restrict__ out, ushort* __restrict__ outb)
{
  int n = blockIdx.x;
  int t = n & (SEQ-1);
  int id = ids[n];
  int tid = threadIdx.x;
  float v[3]; float s1=0.f, s2=0.f;
  #pragma unroll
  for (int j=0;j<3;j++){
    int d = tid + j*128;
    float x = tok[(long)id*DMODEL + d] + pos[t*DMODEL + d] + typ[d];
    v[j]=x; s1+=x; s2+=x*x;
  }
  #pragma unroll
  for (int m=1;m<64;m<<=1){ s1 += __shfl_xor(s1,m); s2 += __shfl_xor(s2,m); }
  __shared__ float r1[2], r2[2];
  if ((tid&63)==0){ r1[tid>>6]=s1; r2[tid>>6]=s2; }
  __syncthreads();
  s1 = r1[0]+r1[1]; s2 = r2[0]+r2[1];
  float mean = s1*(1.f/DMODEL);
  float var  = s2*(1.f/DMODEL) - mean*mean;
  float inv  = rsqrtf(var + 1e-12f);
  #pragma unroll
  for (int j=0;j<3;j++){
    int d = tid + j*128;
    float y = (v[j]-mean)*inv*g[d] + bvec[d];
    out[(long)n*DMODEL + d] = y;
    outb[(long)n*DMODEL + d] = f2b(y);
  }
}

// ---------------- residual add + LN (f32 + bf16 shadow) ----------------
__global__ __launch_bounds__(128) void add_ln_kernel(
    float* __restrict__ h, const float* __restrict__ res,
    const float* __restrict__ g, const float* __restrict__ bvec,
    ushort* __restrict__ hb)
{
  int n = blockIdx.x;
  int tid = threadIdx.x;
  float v[3]; float s1=0.f, s2=0.f;
  #pragma unroll
  for (int j=0;j<3;j++){
    int d = tid + j*128;
    float x = h[(long)n*DMODEL + d] + res[(long)n*DMODEL + d];
    v[j]=x; s1+=x; s2+=x*x;
  }
  #pragma unroll
  for (int m=1;m<64;m<<=1){ s1 += __shfl_xor(s1,m); s2 += __shfl_xor(s2,m); }
  __shared__ float r1[2], r2[2];
  if ((tid&63)==0){ r1[tid>>6]=s1; r2[tid>>6]=s2; }
  __syncthreads();
  s1 = r1[0]+r1[1]; s2 = r2[0]+r2[1];
  float mean = s1*(1.f/DMODEL);
  float var  = s2*(1.f/DMODEL) - mean*mean;
  float inv  = rsqrtf(var + 1e-12f);
  #pragma unroll
  for (int j=0;j<3;j++){
    int d = tid + j*128;
    float y = (v[j]-mean)*inv*g[d] + bvec[d];
    h[(long)n*DMODEL + d] = y;
    hb[(long)n*DMODEL + d] = f2b(y);
  }
}

// ---------------- per-layer weight transpose+convert into bf16 arena ----------------
// WTA (ushort offsets): QKVG rows[1536][384] @0; O [384][384] @589824;
// W1 [1536][384] @737280; W2 [384][1536] @1327104.
__global__ __launch_bounds__(256) void tcvt_all(
    const float* __restrict__ Wq_l, const float* __restrict__ Wk_l,
    const float* __restrict__ Wv_l, const float* __restrict__ Wg_l,
    const float* __restrict__ Wo_l, const float* __restrict__ W1_l,
    const float* __restrict__ W2_l, ushort* __restrict__ WTA)
{
  __shared__ float tile[32][33];
  int bid = blockIdx.x;
  const float* src; long dstbase; int rowlen, Nd, tk, tn, row0;
  if (bid < 720){
    int seg = bid/144, t = bid%144;
    tk = t%12; tn = t/12;
    src = (seg==0)?Wq_l:(seg==1)?Wk_l:(seg==2)?Wv_l:(seg==3)?Wg_l:Wo_l;
    Nd = 384; rowlen = 384;
    if (seg<4){ dstbase=0; row0=seg*384; }
    else      { dstbase=589824; row0=0; }
  } else if (bid < 1296){
    int t = bid-720; tk=t%12; tn=t/12;
    src=W1_l; Nd=DFF; dstbase=737280; row0=0; rowlen=384;
  } else {
    int t = bid-1296; tk=t%48; tn=t/48;
    src=W2_l; Nd=384; dstbase=1327104; row0=0; rowlen=DFF;
  }
  int k0=tk*32, n0=tn*32;
  int tt=threadIdx.x;
  int r=tt>>3, c4=(tt&7)<<2;
  const float* sp = src + (long)(k0+r)*Nd + n0 + c4;
  float4 f = *(const float4*)sp;
  tile[r][c4+0]=f.x; tile[r][c4+1]=f.y; tile[r][c4+2]=f.z; tile[r][c4+3]=f.w;
  __syncthreads();
  ushort4 o;
  o.x=f2b(tile[c4+0][r]); o.y=f2b(tile[c4+1][r]);
  o.z=f2b(tile[c4+2][r]); o.w=f2b(tile[c4+3][r]);
  *(ushort4*)(WTA + dstbase + (long)(row0+n0+r)*rowlen + k0 + c4) = o;
}

// ---------------- bf16 MFMA GEMM, 128x128 tile ----------------
template<int ACT, int OUTBF>
__global__ __launch_bounds__(256) void gemm_bf(
    const ushort* __restrict__ Xb, const ushort* __restrict__ WT,
    const float* __restrict__ bias, void* __restrict__ Cv, int Kd, int Nd)
{
  __shared__ ushort A_lds[128*32];
  __shared__ ushort B_lds[128*32];
  int tid = threadIdx.x;
  int bm = blockIdx.x*128, bn = blockIdx.y*128;
  int w = tid>>6, lane = tid&63;
  int wm = w>>1, wn = w&1;
  f32x4 acc[4][4];
  #pragma unroll
  for (int i=0;i<4;i++)
    #pragma unroll
    for (int j=0;j<4;j++) acc[i][j]=(f32x4)(0.f);

  int cl = lane&15, koff = (lane>>4)*8;
  int srow = w*32 + (lane>>2);
  int scol = (lane&3)*8;
  const ushort* gA0 = Xb + (long)(bm+srow)*Kd + scol;
  const ushort* gA1 = gA0 + 16*(long)Kd;
  const ushort* gB0 = WT + (long)(bn+srow)*Kd + scol;
  const ushort* gB1 = gB0 + 16*(long)Kd;
  ushort* lA = A_lds + w*1024;
  ushort* lB = B_lds + w*1024;

  for (int k0=0; k0<Kd; k0+=32){
    gload16(gA0+k0, lA);
    gload16(gA1+k0, lA+512);
    gload16(gB0+k0, lB);
    gload16(gB1+k0, lB+512);
    __syncthreads();
    short8 bf[4];
    #pragma unroll
    for (int ni=0;ni<4;ni++)
      bf[ni] = *(const short8*)&B_lds[(wn*64+ni*16+cl)*32 + koff];
    #pragma unroll
    for (int mi=0;mi<4;mi++){
      short8 af = *(const short8*)&A_lds[(wm*64+mi*16+cl)*32 + koff];
      #pragma unroll
      for (int ni=0;ni<4;ni++)
        acc[mi][ni] = __builtin_amdgcn_mfma_f32_16x16x32_bf16(af, bf[ni], acc[mi][ni], 0,0,0);
    }
    __syncthreads();
  }

  int rb = (lane>>4)*4;
  #pragma unroll
  for (int ni=0; ni<4; ni++){
    int col = bn + wn*64 + ni*16 + cl;
    float bsv = bias ? bias[col] : 0.f;
    #pragma unroll
    for (int mi=0; mi<4; mi++){
      #pragma unroll
      for (int j=0;j<4;j++){
        int row = bm + wm*64 + mi*16 + rb + j;
        float c = acc[mi][ni][j] + bsv;
        if (ACT==1)      c = c*sigmoidf_(c);
        else if (ACT==2) c = 0.5f*c*(1.f+erff(c*0.70710678118f));
        else if (ACT==3) c = sigmoidf_(c);
        if (OUTBF) ((ushort*)Cv)[(long)row*Nd + col] = f2b(c);
        else       ((float*)Cv)[(long)row*Nd + col] = c;
      }
    }
  }
}

// ---------------- bf16 MFMA GEMM, 128x64 tile (for N=384: 384 blocks) ----------------
template<int ACT, int OUTBF>
__global__ __launch_bounds__(256) void gemm_bf2(
    const ushort* __restrict__ Xb, const ushort* __restrict__ WT,
    const float* __restrict__ bias, void* __restrict__ Cv, int Kd, int Nd)
{
  __shared__ ushort A_lds[128*32];
  __shared__ ushort B_lds[64*32];
  int tid = threadIdx.x;
  int bm = blockIdx.x*128, bn = blockIdx.y*64;
  int w = tid>>6, lane = tid&63;
  int wm = w>>1, wn = w&1;
  f32x4 acc[4][2];
  #pragma unroll
  for (int i=0;i<4;i++){ acc[i][0]=(f32x4)(0.f); acc[i][1]=(f32x4)(0.f); }

  int cl = lane&15, koff = (lane>>4)*8;
  int srowA = w*32 + (lane>>2);
  int scol = (lane&3)*8;
  const ushort* gA0 = Xb + (long)(bm+srowA)*Kd + scol;
  const ushort* gA1 = gA0 + 16*(long)Kd;
  int srowB = w*16 + (lane>>2);
  const ushort* gB = WT + (long)(bn+srowB)*Kd + scol;
  ushort* lA = A_lds + w*1024;
  ushort* lB = B_lds + w*512;

  for (int k0=0; k0<Kd; k0+=32){
    gload16(gA0+k0, lA);
    gload16(gA1+k0, lA+512);
    gload16(gB+k0, lB);
    __syncthreads();
    short8 b0 = *(const short8*)&B_lds[(wn*32+cl)*32 + koff];
    short8 b1 = *(const short8*)&B_lds[(wn*32+16+cl)*32 + koff];
    #pragma unroll
    for (int mi=0;mi<4;mi++){
      short8 af = *(const short8*)&A_lds[(wm*64+mi*16+cl)*32 + koff];
      acc[mi][0] = __builtin_amdgcn_mfma_f32_16x16x32_bf16(af, b0, acc[mi][0], 0,0,0);
      acc[mi][1] = __builtin_amdgcn_mfma_f32_16x16x32_bf16(af, b1, acc[mi][1], 0,0,0);
    }
    __syncthreads();
  }

  int rb = (lane>>4)*4;
  #pragma unroll
  for (int ni=0; ni<2; ni++){
    int col = bn + wn*32 + ni*16 + cl;
    float bsv = bias ? bias[col] : 0.f;
    #pragma unroll
    for (int mi=0; mi<4; mi++){
      #pragma unroll
      for (int j=0;j<4;j++){
        int row = bm + wm*64 + mi*16 + rb + j;
        float c = acc[mi][ni][j] + bsv;
        if (ACT==1)      c = c*sigmoidf_(c);
        else if (ACT==2) c = 0.5f*c*(1.f+erff(c*0.70710678118f));
        else if (ACT==3) c = sigmoidf_(c);
        if (OUTBF) ((ushort*)Cv)[(long)row*Nd + col] = f2b(c);
        else       ((float*)Cv)[(long)row*Nd + col] = c;
      }
    }
  }
}

// ---------------- fused QKVG GEMM (f32 out, per-segment act/bias) ----------------
__global__ __launch_bounds__(256) void gemm_qkvg(
    const ushort* __restrict__ Xb, const ushort* __restrict__ WT,
    const float* __restrict__ bq, const float* __restrict__ bk,
    const float* __restrict__ bv, float* __restrict__ C)
{
  __shared__ ushort A_lds[128*32];
  __shared__ ushort B_lds[128*32];
  int tid = threadIdx.x;
  int bm = blockIdx.x*128, bn = blockIdx.y*128;
  int w = tid>>6, lane = tid&63;
  int wm = w>>1, wn = w&1;
  f32x4 acc[4][4];
  #pragma unroll
  for (int i=0;i<4;i++)
    #pragma unroll
    for (int j=0;j<4;j++) acc[i][j]=(f32x4)(0.f);

  int cl = lane&15, koff = (lane>>4)*8;
  int srow = w*32 + (lane>>2);
  int scol = (lane&3)*8;
  const ushort* gA0 = Xb + (long)(bm+srow)*DMODEL + scol;
  const ushort* gA1 = gA0 + 16*DMODEL;
  const ushort* gB0 = WT + (long)(bn+srow)*DMODEL + scol;
  const ushort* gB1 = gB0 + 16*DMODEL;
  ushort* lA = A_lds + w*1024;
  ushort* lB = B_lds + w*1024;

  for (int k0=0; k0<DMODEL; k0+=32){
    gload16(gA0+k0, lA);
    gload16(gA1+k0, lA+512);
    gload16(gB0+k0, lB);
    gload16(gB1+k0, lB+512);
    __syncthreads();
    short8 bf[4];
    #pragma unroll
    for (int ni=0;ni<4;ni++)
      bf[ni] = *(const short8*)&B_lds[(wn*64+ni*16+cl)*32 + koff];
    #pragma unroll
    for (int mi=0;mi<4;mi++){
      short8 af = *(const short8*)&A_lds[(wm*64+mi*16+cl)*32 + koff];
      #pragma unroll
      for (int ni=0;ni<4;ni++)
        acc[mi][ni] = __builtin_amdgcn_mfma_f32_16x16x32_bf16(af, bf[ni], acc[mi][ni], 0,0,0);
    }
    __syncthreads();
  }

  int seg = blockIdx.y/3;
  const float* bp = (seg==0)?bq:(seg==1)?bk:(seg==2)?bv:nullptr;
  int boff = seg*384;
  int rb = (lane>>4)*4;
  #pragma unroll
  for (int ni=0; ni<4; ni++){
    int col = bn + wn*64 + ni*16 + cl;
    float bsv = bp ? bp[col-boff] : 0.f;
    #pragma unroll
    for (int mi=0; mi<4; mi++){
      #pragma unroll
      for (int j=0;j<4;j++){
        int row = bm + wm*64 + mi*16 + rb + j;
        float c = acc[mi][ni][j] + bsv;
        if (seg<2)       c = c*sigmoidf_(c);
        else if (seg==3) c = sigmoidf_(c);
        C[(long)row*DFF + col] = c;
      }
    }
  }
}

// ---------------- fused aux: knorm (blocks 0..8191) + beta (blocks 8192..16383) ----------
__global__ __launch_bounds__(384) void aux_kernel(
    float* __restrict__ QKVG, const float* __restrict__ X,
    const float* __restrict__ Wb, const float* __restrict__ bb,
    const int* __restrict__ mask, float* __restrict__ Bb)
{
  int bid = blockIdx.x;
  int tid = threadIdx.x;
  if (bid < NTOK){
    long a = (long)bid*DFF + 384 + tid;
    float x = QKVG[a];
    float ss = x*x;
    #pragma unroll
    for (int m=1;m<32;m<<=1) ss += __shfl_xor(ss,m);
    QKVG[a] = x / (sqrtf(ss)+1e-6f);
  } else {
    int n = bid - NTOK;
    __shared__ float xs[DMODEL];
    xs[tid] = X[(long)n*DMODEL + tid];
    __syncthreads();
    int hh = tid >> 5, i = tid & 31;
    float s = 0.f;
    for (int d=i; d<DMODEL; d+=32) s += xs[d]*Wb[d*NHEAD+hh];
    #pragma unroll
    for (int m=1;m<32;m<<=1) s += __shfl_xor(s,m);
    if (i==0) Bb[n*NHEAD+hh] = (float)mask[n] * sigmoidf_(s + bb[hh]);
  }
}

// ---------------- delta-rule scan v7: scan6 + sched_barrier load-issue pinning -------
// 192 blocks = (b,h); 512 thr = 8 waves: st = w>>2, vq = w&3.
// lane: kq = lane&7 (k = kq*4..+3), v = vq*8 + (lane>>3). S[4] in regs.
__device__ __forceinline__ void load_group(
    const float* __restrict__ rp0, const float* __restrict__ bp0,
    int hh, int kq, int v,
    float4 (&kk)[8], float4 (&qq)[8], float (&vv)[8], float (&bb)[8])
{
  #pragma unroll
  for (int i=0;i<8;i++){
    const float* rp = rp0 + (long)i*DFF;
    qq[i] = *(const float4*)(rp + hh*32 + kq*4);
    kk[i] = *(const float4*)(rp + 384 + hh*32 + kq*4);
    vv[i] = rp[768 + hh*32 + v];
    bb[i] = bp0[i*NHEAD];
  }
}
__device__ __forceinline__ void steps8(
    float4 (&kk)[8], float4 (&qq)[8], float (&vv)[8], float (&bb)[8],
    float dec, float (&S)[4], int st, int v, int kq, int tloc,
    float (&Ofs)[2][64][36])
{
  #pragma unroll
  for (int i=0;i<8;i++){
    float4 k4=kk[i], q4=qq[i];
    float pa = k4.x*S[0] + k4.y*S[1];
    float pb = k4.z*S[2] + k4.w*S[3];
    float p = red8(pa+pb);
    float err = (vv[i]-p)*bb[i];
    S[0] = dec*S[0] + k4.x*err;
    S[1] = dec*S[1] + k4.y*err;
    S[2] = dec*S[2] + k4.z*err;
    S[3] = dec*S[3] + k4.w*err;
    float oa = q4.x*S[0] + q4.y*S[1];
    float ob = q4.z*S[2] + q4.w*S[3];
    float o = red8(oa+ob);
    if (kq==0) Ofs[st][tloc+i][v] = o;
  }
}

__global__ __launch_bounds__(512,2) void scan7_kernel(
    const float* __restrict__ QKVG, const float* __restrict__ Bb,
    const float* __restrict__ dfl, const float* __restrict__ dsl,
    const float* __restrict__ mixl, ushort* __restrict__ OA)
{
  __shared__ float Ofs[2][64][36];
  int bh = blockIdx.x;
  int b = bh / NHEAD, hh = bh - b*NHEAD;
  int tid = threadIdx.x;
  int w = tid>>6, lane = tid&63;
  int st = w>>2, vq = w&3;
  int kq = lane&7, v = vq*8 + (lane>>3);
  float dec = sigmoidf_(st ? dsl[hh] : dfl[hh]);
  float mix = sigmoidf_(mixl[hh]);
  long rowbase = (long)b*SEQ;
  const float* rp = QKVG + rowbase*DFF;
  const float* bp = Bb + rowbase*NHEAD + hh;

  float S[4] = {0.f,0.f,0.f,0.f};
  float4 kA[8],qA[8],kB[8],qB[8];
  float  vA[8],bA[8],vB[8],bB[8];

  load_group(rp, bp, hh, kq, v, kA, qA, vA, bA);
  __builtin_amdgcn_sched_barrier(0);
  for (int gg=0; gg<64; gg+=2){
    load_group(rp + (long)(gg+1)*8*DFF, bp + (gg+1)*8*NHEAD, hh, kq, v, kB, qB, vB, bB);
    __builtin_amdgcn_sched_barrier(0);   // pin: B-loads issued before A-compute
    steps8(kA,qA,vA,bA, dec, S, st, v, kq, (gg*8)&63, Ofs);
    __builtin_amdgcn_sched_barrier(0);
    if (gg+2<64){
      load_group(rp + (long)(gg+2)*8*DFF, bp + (gg+2)*8*NHEAD, hh, kq, v, kA, qA, vA, bA);
      __builtin_amdgcn_sched_barrier(0); // pin: A-loads issued before B-compute
    }
    steps8(kB,qB,vB,bB, dec, S, st, v, kq, (gg*8+8)&63, Ofs);
    if (((gg+1)&7)==7){
      int cidx = (gg+1)>>3;
      __syncthreads();
      int t = tid>>3, v0 = (tid&7)<<2;
      long r = rowbase + cidx*64 + t;
      float4 g4 = *(const float4*)(QKVG + r*DFF + 1152 + hh*32 + v0);
      float4 of = *(const float4*)&Ofs[0][t][v0];
      float4 os = *(const float4*)&Ofs[1][t][v0];
      float a0 = (mix*of.x + (1.f-mix)*os.x)*g4.x;
      float a1 = (mix*of.y + (1.f-mix)*os.y)*g4.y;
      float a2 = (mix*of.z + (1.f-mix)*os.z)*g4.z;
      float a3 = (mix*of.w + (1.f-mix)*os.w)*g4.w;
      uint2 o2; o2.x = pk2(a0,a1); o2.y = pk2(a2,a3);
      *(uint2*)(OA + r*DMODEL + hh*32 + v0) = o2;
      __syncthreads();
    }
  }
}

// ---------------- masked mean pool + L2 normalize ----------------
__global__ __launch_bounds__(384) void pool_norm_kernel(
    const float* __restrict__ h, const int* __restrict__ mask, float* __restrict__ out)
{
  int b = blockIdx.x; int d = threadIdx.x;
  float s=0.f, ms=0.f;
  for (int t=0;t<SEQ;t++){
    float m = (float)mask[b*SEQ+t];
    s += h[((long)b*SEQ+t)*DMODEL + d]*m;
    ms += m;
  }
  float emb = s / fmaxf(ms, 1e-9f);
  float ss = emb*emb;
  #pragma unroll
  for (int m2=1;m2<64;m2<<=1) ss += __shfl_xor(ss,m2);
  __shared__ float r[6];
  if ((d&63)==0) r[d>>6]=ss;
  __syncthreads();
  ss = r[0]+r[1]+r[2]+r[3]+r[4]+r[5];
  out[b*DMODEL+d] = emb / (sqrtf(ss)+1e-12f);
}

extern "C" void kernel_launch(void* const* d_in, const int* in_sizes, int n_in,
                              void* d_out, int out_size, void* d_ws, size_t ws_size,
                              hipStream_t stream)
{
  const int*   ids   = (const int*)d_in[0];
  const int*   amask = (const int*)d_in[1];
  const float* etok  = (const float*)d_in[2];
  const float* epos  = (const float*)d_in[3];
  const float* etyp  = (const float*)d_in[4];
  const float* elng  = (const float*)d_in[5];
  const float* elnb  = (const float*)d_in[6];
  const float* Wq = (const float*)d_in[7];  const float* bq = (const float*)d_in[8];
  const float* Wk = (const float*)d_in[9];  const float* bk = (const float*)d_in[10];
  const float* Wv = (const float*)d_in[11]; const float* bv = (const float*)d_in[12];
  const float* Wb = (const float*)d_in[13]; const float* bb = (const float*)d_in[14];
  const float* dfl = (const float*)d_in[15];
  const float* dsl = (const float*)d_in[16];
  const float* mixl= (const float*)d_in[17];
  const float* Wg = (const float*)d_in[18];
  const float* Wo = (const float*)d_in[19]; const float* bo = (const float*)d_in[20];
  const float* alng = (const float*)d_in[21]; const float* alnb = (const float*)d_in[22];
  const float* W1 = (const float*)d_in[23]; const float* b1 = (const float*)d_in[24];
  const float* W2 = (const float*)d_in[25]; const float* b2 = (const float*)d_in[26];
  const float* flng = (const float*)d_in[27]; const float* flnb = (const float*)d_in[28];

  float* ws = (float*)d_ws;
  const long TD = (long)NTOK*DMODEL;
  float* h    = ws;                            // [8192][384] f32
  ushort* hbf = (ushort*)(h + TD);             // [8192][384] bf16
  float* QKVG = h + TD + TD/2;                 // [8192][1536] f32
  ushort* OA  = (ushort*)(QKVG + 4*TD);        // [8192][384] bf16
  float* Rb   = QKVG + 4*TD + TD/2;            // attn/ffn output f32
  float* Bb   = Rb + TD;                       // [8192][12]
  ushort* WTA = (ushort*)(Bb + (long)NTOK*NHEAD);
  ushort* F1B = (ushort*)QKVG;                 // FFN mid bf16, aliases dead QKVG

  embed_ln_kernel<<<NTOK,128,0,stream>>>(ids, etok, epos, etyp, elng, elnb, h, hbf);

  for (int l=0;l<NLAYER;l++){
    tcvt_all<<<1872,256,0,stream>>>(
        Wq + (long)l*DMODEL*DMODEL, Wk + (long)l*DMODEL*DMODEL,
        Wv + (long)l*DMODEL*DMODEL, Wg + (long)l*DMODEL*DMODEL,
        Wo + (long)l*DMODEL*DMODEL, W1 + (long)l*DMODEL*DFF,
        W2 + (long)l*DFF*DMODEL, WTA);
    gemm_qkvg<<<dim3(64,12),256,0,stream>>>(hbf, WTA, bq+l*DMODEL, bk+l*DMODEL, bv+l*DMODEL, QKVG);
    aux_kernel<<<2*NTOK,384,0,stream>>>(QKVG, h, Wb + (long)l*DMODEL*NHEAD, bb + l*NHEAD, amask, Bb);
    scan7_kernel<<<BATCH*NHEAD,512,0,stream>>>(QKVG, Bb, dfl + l*NHEAD, dsl + l*NHEAD, mixl + l*NHEAD, OA);
    gemm_bf2<0,0><<<dim3(64,6),256,0,stream>>>(OA, WTA+589824, bo + l*DMODEL, Rb, DMODEL, DMODEL);
    add_ln_kernel<<<NTOK,128,0,stream>>>(h, Rb, alng + (long)l*DMODEL, alnb + (long)l*DMODEL, hbf);
    gemm_bf<2,1><<<dim3(64,12),256,0,stream>>>(hbf, WTA+737280, b1 + (long)l*DFF, F1B, DMODEL, DFF);
    gemm_bf2<0,0><<<dim3(64,6),256,0,stream>>>(F1B, WTA+1327104, b2 + (long)l*DMODEL, Rb, DFF, DMODEL);
    add_ln_kernel<<<NTOK,128,0,stream>>>(h, Rb, flng + (long)l*DMODEL, flnb + (long)l*DMODEL, hbf);
  }

  pool_norm_kernel<<<BATCH,384,0,stream>>>(h, amask, (float*)d_out);
}

// Round 8
// 1415.658 us; speedup vs baseline: 1.4112x; 1.0772x over previous
//
#include <hip/hip_runtime.h>
#include <hip/hip_bf16.h>

#define NTOK   8192
#define DMODEL 384
#define NHEAD  12
#define DHEAD  32
#define NLAYER 6
#define DFF    1536
#define SEQ    512
#define BATCH  16
#define TCH    32
#define WTAL   1916928L

typedef __attribute__((ext_vector_type(8))) short short8;
typedef __attribute__((ext_vector_type(4))) float f32x4;

__device__ __forceinline__ float sigmoidf_(float x){ return 1.f/(1.f+expf(-x)); }

__device__ __forceinline__ ushort f2b(float x){
  uint b = __builtin_bit_cast(uint, x);
  uint r = (b + 0x7FFFu + ((b>>16)&1u)) >> 16;
  return (ushort)r;
}
__device__ __forceinline__ uint pk2(float lo, float hi){
  return (uint)f2b(lo) | ((uint)f2b(hi)<<16);
}
// 8-lane sum: quad_perm xor1, quad_perm xor2, row_half_mirror
__device__ __forceinline__ float red8(float x){
  int t = __builtin_amdgcn_update_dpp(0, __builtin_bit_cast(int,x), 0xB1, 0xF, 0xF, true);
  x += __builtin_bit_cast(float,t);
  t = __builtin_amdgcn_update_dpp(0, __builtin_bit_cast(int,x), 0x4E, 0xF, 0xF, true);
  x += __builtin_bit_cast(float,t);
  t = __builtin_amdgcn_update_dpp(0, __builtin_bit_cast(int,x), 0x141, 0xF, 0xF, true);
  x += __builtin_bit_cast(float,t);
  return x;
}
__device__ __forceinline__ void gload16(const ushort* g, ushort* l){
  __builtin_amdgcn_global_load_lds((const __attribute__((address_space(1))) void*)g,
                                   (__attribute__((address_space(3))) void*)l, 16, 0, 0);
}

// ---------------- embedding + LN (f32 + bf16 shadow) ----------------
__global__ __launch_bounds__(128) void embed_ln_kernel(
    const int* __restrict__ ids, const float* __restrict__ tok,
    const float* __restrict__ pos, const float* __restrict__ typ,
    const float* __restrict__ g, const float* __restrict__ bvec,
    float* __restrict__ out, ushort* __restrict__ outb)
{
  int n = blockIdx.x;
  int t = n & (SEQ-1);
  int id = ids[n];
  int tid = threadIdx.x;
  float v[3]; float s1=0.f, s2=0.f;
  #pragma unroll
  for (int j=0;j<3;j++){
    int d = tid + j*128;
    float x = tok[(long)id*DMODEL + d] + pos[t*DMODEL + d] + typ[d];
    v[j]=x; s1+=x; s2+=x*x;
  }
  #pragma unroll
  for (int m=1;m<64;m<<=1){ s1 += __shfl_xor(s1,m); s2 += __shfl_xor(s2,m); }
  __shared__ float r1[2], r2[2];
  if ((tid&63)==0){ r1[tid>>6]=s1; r2[tid>>6]=s2; }
  __syncthreads();
  s1 = r1[0]+r1[1]; s2 = r2[0]+r2[1];
  float mean = s1*(1.f/DMODEL);
  float var  = s2*(1.f/DMODEL) - mean*mean;
  float inv  = rsqrtf(var + 1e-12f);
  #pragma unroll
  for (int j=0;j<3;j++){
    int d = tid + j*128;
    float y = (v[j]-mean)*inv*g[d] + bvec[d];
    out[(long)n*DMODEL + d] = y;
    outb[(long)n*DMODEL + d] = f2b(y);
  }
}

// ---------------- residual add + LN (f32 + bf16 shadow) ----------------
__global__ __launch_bounds__(128) void add_ln_kernel(
    float* __restrict__ h, const float* __restrict__ res,
    const float* __restrict__ g, const float* __restrict__ bvec,
    ushort* __restrict__ hb)
{
  int n = blockIdx.x;
  int tid = threadIdx.x;
  float v[3]; float s1=0.f, s2=0.f;
  #pragma unroll
  for (int j=0;j<3;j++){
    int d = tid + j*128;
    float x = h[(long)n*DMODEL + d] + res[(long)n*DMODEL + d];
    v[j]=x; s1+=x; s2+=x*x;
  }
  #pragma unroll
  for (int m=1;m<64;m<<=1){ s1 += __shfl_xor(s1,m); s2 += __shfl_xor(s2,m); }
  __shared__ float r1[2], r2[2];
  if ((tid&63)==0){ r1[tid>>6]=s1; r2[tid>>6]=s2; }
  __syncthreads();
  s1 = r1[0]+r1[1]; s2 = r2[0]+r2[1];
  float mean = s1*(1.f/DMODEL);
  float var  = s2*(1.f/DMODEL) - mean*mean;
  float inv  = rsqrtf(var + 1e-12f);
  #pragma unroll
  for (int j=0;j<3;j++){
    int d = tid + j*128;
    float y = (v[j]-mean)*inv*g[d] + bvec[d];
    h[(long)n*DMODEL + d] = y;
    hb[(long)n*DMODEL + d] = f2b(y);
  }
}

// ---------------- ALL-layer weight transpose+convert (runs once) ----------------
// Per layer l, WTA_l = WTA + l*WTAL (ushort offsets): QKVG rows[1536][384] @0;
// O [384][384] @589824; W1 [1536][384] @737280; W2 [384][1536] @1327104.
__global__ __launch_bounds__(256) void tcvt6(
    const float* __restrict__ Wq, const float* __restrict__ Wk,
    const float* __restrict__ Wv, const float* __restrict__ Wg,
    const float* __restrict__ Wo, const float* __restrict__ W1,
    const float* __restrict__ W2, ushort* __restrict__ WTA)
{
  __shared__ float tile[32][33];
  int l = blockIdx.x / 1872;
  int bid = blockIdx.x % 1872;
  const float* Wq_l = Wq + (long)l*DMODEL*DMODEL;
  const float* Wk_l = Wk + (long)l*DMODEL*DMODEL;
  const float* Wv_l = Wv + (long)l*DMODEL*DMODEL;
  const float* Wg_l = Wg + (long)l*DMODEL*DMODEL;
  const float* Wo_l = Wo + (long)l*DMODEL*DMODEL;
  const float* W1_l = W1 + (long)l*DMODEL*DFF;
  const float* W2_l = W2 + (long)l*DFF*DMODEL;
  ushort* WTAl = WTA + (long)l*WTAL;

  const float* src; long dstbase; int rowlen, Nd, tk, tn, row0;
  if (bid < 720){
    int seg = bid/144, t = bid%144;
    tk = t%12; tn = t/12;
    src = (seg==0)?Wq_l:(seg==1)?Wk_l:(seg==2)?Wv_l:(seg==3)?Wg_l:Wo_l;
    Nd = 384; rowlen = 384;
    if (seg<4){ dstbase=0; row0=seg*384; }
    else      { dstbase=589824; row0=0; }
  } else if (bid < 1296){
    int t = bid-720; tk=t%12; tn=t/12;
    src=W1_l; Nd=DFF; dstbase=737280; row0=0; rowlen=384;
  } else {
    int t = bid-1296; tk=t%48; tn=t/48;
    src=W2_l; Nd=384; dstbase=1327104; row0=0; rowlen=DFF;
  }
  int k0=tk*32, n0=tn*32;
  int tt=threadIdx.x;
  int r=tt>>3, c4=(tt&7)<<2;
  const float* sp = src + (long)(k0+r)*Nd + n0 + c4;
  float4 f = *(const float4*)sp;
  tile[r][c4+0]=f.x; tile[r][c4+1]=f.y; tile[r][c4+2]=f.z; tile[r][c4+3]=f.w;
  __syncthreads();
  ushort4 o;
  o.x=f2b(tile[c4+0][r]); o.y=f2b(tile[c4+1][r]);
  o.z=f2b(tile[c4+2][r]); o.w=f2b(tile[c4+3][r]);
  *(ushort4*)(WTAl + dstbase + (long)(row0+n0+r)*rowlen + k0 + c4) = o;
}

// ---------------- bf16 MFMA GEMM, 128x128 tile ----------------
template<int ACT, int OUTBF>
__global__ __launch_bounds__(256) void gemm_bf(
    const ushort* __restrict__ Xb, const ushort* __restrict__ WT,
    const float* __restrict__ bias, void* __restrict__ Cv, int Kd, int Nd)
{
  __shared__ ushort A_lds[128*32];
  __shared__ ushort B_lds[128*32];
  int tid = threadIdx.x;
  int bm = blockIdx.x*128, bn = blockIdx.y*128;
  int w = tid>>6, lane = tid&63;
  int wm = w>>1, wn = w&1;
  f32x4 acc[4][4];
  #pragma unroll
  for (int i=0;i<4;i++)
    #pragma unroll
    for (int j=0;j<4;j++) acc[i][j]=(f32x4)(0.f);

  int cl = lane&15, koff = (lane>>4)*8;
  int srow = w*32 + (lane>>2);
  int scol = (lane&3)*8;
  const ushort* gA0 = Xb + (long)(bm+srow)*Kd + scol;
  const ushort* gA1 = gA0 + 16*(long)Kd;
  const ushort* gB0 = WT + (long)(bn+srow)*Kd + scol;
  const ushort* gB1 = gB0 + 16*(long)Kd;
  ushort* lA = A_lds + w*1024;
  ushort* lB = B_lds + w*1024;

  for (int k0=0; k0<Kd; k0+=32){
    gload16(gA0+k0, lA);
    gload16(gA1+k0, lA+512);
    gload16(gB0+k0, lB);
    gload16(gB1+k0, lB+512);
    __syncthreads();
    short8 bf[4];
    #pragma unroll
    for (int ni=0;ni<4;ni++)
      bf[ni] = *(const short8*)&B_lds[(wn*64+ni*16+cl)*32 + koff];
    #pragma unroll
    for (int mi=0;mi<4;mi++){
      short8 af = *(const short8*)&A_lds[(wm*64+mi*16+cl)*32 + koff];
      #pragma unroll
      for (int ni=0;ni<4;ni++)
        acc[mi][ni] = __builtin_amdgcn_mfma_f32_16x16x32_bf16(af, bf[ni], acc[mi][ni], 0,0,0);
    }
    __syncthreads();
  }

  int rb = (lane>>4)*4;
  #pragma unroll
  for (int ni=0; ni<4; ni++){
    int col = bn + wn*64 + ni*16 + cl;
    float bsv = bias ? bias[col] : 0.f;
    #pragma unroll
    for (int mi=0; mi<4; mi++){
      #pragma unroll
      for (int j=0;j<4;j++){
        int row = bm + wm*64 + mi*16 + rb + j;
        float c = acc[mi][ni][j] + bsv;
        if (ACT==1)      c = c*sigmoidf_(c);
        else if (ACT==2) c = 0.5f*c*(1.f+erff(c*0.70710678118f));
        else if (ACT==3) c = sigmoidf_(c);
        if (OUTBF) ((ushort*)Cv)[(long)row*Nd + col] = f2b(c);
        else       ((float*)Cv)[(long)row*Nd + col] = c;
      }
    }
  }
}

// ---------------- bf16 MFMA GEMM, 128x64 tile ----------------
template<int ACT, int OUTBF>
__global__ __launch_bounds__(256) void gemm_bf2(
    const ushort* __restrict__ Xb, const ushort* __restrict__ WT,
    const float* __restrict__ bias, void* __restrict__ Cv, int Kd, int Nd)
{
  __shared__ ushort A_lds[128*32];
  __shared__ ushort B_lds[64*32];
  int tid = threadIdx.x;
  int bm = blockIdx.x*128, bn = blockIdx.y*64;
  int w = tid>>6, lane = tid&63;
  int wm = w>>1, wn = w&1;
  f32x4 acc[4][2];
  #pragma unroll
  for (int i=0;i<4;i++){ acc[i][0]=(f32x4)(0.f); acc[i][1]=(f32x4)(0.f); }

  int cl = lane&15, koff = (lane>>4)*8;
  int srowA = w*32 + (lane>>2);
  int scol = (lane&3)*8;
  const ushort* gA0 = Xb + (long)(bm+srowA)*Kd + scol;
  const ushort* gA1 = gA0 + 16*(long)Kd;
  int srowB = w*16 + (lane>>2);
  const ushort* gB = WT + (long)(bn+srowB)*Kd + scol;
  ushort* lA = A_lds + w*1024;
  ushort* lB = B_lds + w*512;

  for (int k0=0; k0<Kd; k0+=32){
    gload16(gA0+k0, lA);
    gload16(gA1+k0, lA+512);
    gload16(gB+k0, lB);
    __syncthreads();
    short8 b0 = *(const short8*)&B_lds[(wn*32+cl)*32 + koff];
    short8 b1 = *(const short8*)&B_lds[(wn*32+16+cl)*32 + koff];
    #pragma unroll
    for (int mi=0;mi<4;mi++){
      short8 af = *(const short8*)&A_lds[(wm*64+mi*16+cl)*32 + koff];
      acc[mi][0] = __builtin_amdgcn_mfma_f32_16x16x32_bf16(af, b0, acc[mi][0], 0,0,0);
      acc[mi][1] = __builtin_amdgcn_mfma_f32_16x16x32_bf16(af, b1, acc[mi][1], 0,0,0);
    }
    __syncthreads();
  }

  int rb = (lane>>4)*4;
  #pragma unroll
  for (int ni=0; ni<2; ni++){
    int col = bn + wn*32 + ni*16 + cl;
    float bsv = bias ? bias[col] : 0.f;
    #pragma unroll
    for (int mi=0; mi<4; mi++){
      #pragma unroll
      for (int j=0;j<4;j++){
        int row = bm + wm*64 + mi*16 + rb + j;
        float c = acc[mi][ni][j] + bsv;
        if (ACT==1)      c = c*sigmoidf_(c);
        else if (ACT==2) c = 0.5f*c*(1.f+erff(c*0.70710678118f));
        else if (ACT==3) c = sigmoidf_(c);
        if (OUTBF) ((ushort*)Cv)[(long)row*Nd + col] = f2b(c);
        else       ((float*)Cv)[(long)row*Nd + col] = c;
      }
    }
  }
}

// ---------------- fused QKVG GEMM (f32 out, per-segment act/bias) ----------------
__global__ __launch_bounds__(256) void gemm_qkvg(
    const ushort* __restrict__ Xb, const ushort* __restrict__ WT,
    const float* __restrict__ bq, const float* __restrict__ bk,
    const float* __restrict__ bv, float* __restrict__ C)
{
  __shared__ ushort A_lds[128*32];
  __shared__ ushort B_lds[128*32];
  int tid = threadIdx.x;
  int bm = blockIdx.x*128, bn = blockIdx.y*128;
  int w = tid>>6, lane = tid&63;
  int wm = w>>1, wn = w&1;
  f32x4 acc[4][4];
  #pragma unroll
  for (int i=0;i<4;i++)
    #pragma unroll
    for (int j=0;j<4;j++) acc[i][j]=(f32x4)(0.f);

  int cl = lane&15, koff = (lane>>4)*8;
  int srow = w*32 + (lane>>2);
  int scol = (lane&3)*8;
  const ushort* gA0 = Xb + (long)(bm+srow)*DMODEL + scol;
  const ushort* gA1 = gA0 + 16*DMODEL;
  const ushort* gB0 = WT + (long)(bn+srow)*DMODEL + scol;
  const ushort* gB1 = gB0 + 16*DMODEL;
  ushort* lA = A_lds + w*1024;
  ushort* lB = B_lds + w*1024;

  for (int k0=0; k0<DMODEL; k0+=32){
    gload16(gA0+k0, lA);
    gload16(gA1+k0, lA+512);
    gload16(gB0+k0, lB);
    gload16(gB1+k0, lB+512);
    __syncthreads();
    short8 bf[4];
    #pragma unroll
    for (int ni=0;ni<4;ni++)
      bf[ni] = *(const short8*)&B_lds[(wn*64+ni*16+cl)*32 + koff];
    #pragma unroll
    for (int mi=0;mi<4;mi++){
      short8 af = *(const short8*)&A_lds[(wm*64+mi*16+cl)*32 + koff];
      #pragma unroll
      for (int ni=0;ni<4;ni++)
        acc[mi][ni] = __builtin_amdgcn_mfma_f32_16x16x32_bf16(af, bf[ni], acc[mi][ni], 0,0,0);
    }
    __syncthreads();
  }

  int seg = blockIdx.y/3;
  const float* bp = (seg==0)?bq:(seg==1)?bk:(seg==2)?bv:nullptr;
  int boff = seg*384;
  int rb = (lane>>4)*4;
  #pragma unroll
  for (int ni=0; ni<4; ni++){
    int col = bn + wn*64 + ni*16 + cl;
    float bsv = bp ? bp[col-boff] : 0.f;
    #pragma unroll
    for (int mi=0; mi<4; mi++){
      #pragma unroll
      for (int j=0;j<4;j++){
        int row = bm + wm*64 + mi*16 + rb + j;
        float c = acc[mi][ni][j] + bsv;
        if (seg<2)       c = c*sigmoidf_(c);
        else if (seg==3) c = sigmoidf_(c);
        C[(long)row*DFF + col] = c;
      }
    }
  }
}

// ---------------- fused aux: knorm (blocks 0..8191) + beta (blocks 8192..16383) ----------
__global__ __launch_bounds__(384) void aux_kernel(
    float* __restrict__ QKVG, const float* __restrict__ X,
    const float* __restrict__ Wb, const float* __restrict__ bb,
    const int* __restrict__ mask, float* __restrict__ Bb)
{
  int bid = blockIdx.x;
  int tid = threadIdx.x;
  if (bid < NTOK){
    long a = (long)bid*DFF + 384 + tid;
    float x = QKVG[a];
    float ss = x*x;
    #pragma unroll
    for (int m=1;m<32;m<<=1) ss += __shfl_xor(ss,m);
    QKVG[a] = x / (sqrtf(ss)+1e-6f);
  } else {
    int n = bid - NTOK;
    __shared__ float xs[DMODEL];
    xs[tid] = X[(long)n*DMODEL + tid];
    __syncthreads();
    int hh = tid >> 5, i = tid & 31;
    float s = 0.f;
    for (int d=i; d<DMODEL; d+=32) s += xs[d]*Wb[d*NHEAD+hh];
    #pragma unroll
    for (int m=1;m<32;m<<=1) s += __shfl_xor(s,m);
    if (i==0) Bb[n*NHEAD+hh] = (float)mask[n] * sigmoidf_(s + bb[hh]);
  }
}

// ---------------- delta-rule scan v8: 8 waves + LDS chunk staging (TC=32, dbuf) -------
// 192 blocks = (b,h); 512 thr = 8 waves: st = w>>2, vq = w&3.
// lane: kq = lane&7 (k = kq*4..+3), v = vq*8 + (lane>>3). S[4] in regs.
// Staging roles: tid<256: q-slot + v-slot; tid 256..511: k-slot; tid>=480: beta row.
__global__ __launch_bounds__(512,2) void scan8_kernel(
    const float* __restrict__ QKVG, const float* __restrict__ Bb,
    const float* __restrict__ dfl, const float* __restrict__ dsl,
    const float* __restrict__ mixl, ushort* __restrict__ OA)
{
  __shared__ float Qc[2][TCH][36], Kc[2][TCH][36], Vc[2][TCH][36];
  __shared__ float Bc[2][TCH];
  __shared__ float Ofs[2][TCH][36];
  int bh = blockIdx.x;
  int b = bh / NHEAD, hh = bh - b*NHEAD;
  int tid = threadIdx.x;
  int w = tid>>6, lane = tid&63;
  int st = w>>2, vq = w&3;
  int kq = lane&7, v = vq*8 + (lane>>3);
  float dec = sigmoidf_(st ? dsl[hh] : dfl[hh]);
  float mix = sigmoidf_(mixl[hh]);
  long rowbase = (long)b*SEQ;
  const float* rp = QKVG + rowbase*DFF + hh*32;
  const float* bp = Bb + rowbase*NHEAD + hh;

  int rem0 = tid & 255, r0 = rem0>>3, c40 = (rem0&7)<<2;
  bool isK = tid >= 256;
  int brow = tid - 480;
  int et = tid>>3, ev0 = (tid&7)<<2;       // epilogue indices (tid<256)

  float S[4] = {0.f,0.f,0.f,0.f};

  // prologue: stage chunk 0 into buf 0
  {
    float4 a0 = *(const float4*)(rp + (long)r0*DFF + (isK?384:0) + c40);
    float4 v0m = a0;
    if (!isK) v0m = *(const float4*)(rp + (long)r0*DFF + 768 + c40);
    float bb0 = 0.f;
    if (tid>=480) bb0 = bp[(long)brow*NHEAD];
    if (isK) *(float4*)&Kc[0][r0][c40] = a0;
    else { *(float4*)&Qc[0][r0][c40] = a0; *(float4*)&Vc[0][r0][c40] = v0m; }
    if (tid>=480) Bc[0][brow] = bb0;
  }
  __syncthreads();

  for (int c=0; c<SEQ/TCH; ++c){
    int cur = c&1;
    // issue next-chunk loads + epilogue gate load early (latency hides under compute)
    float4 nA, nV; float nB = 0.f;
    if (c+1 < SEQ/TCH){
      long rb2 = (long)((c+1)*TCH + r0)*DFF;
      nA = *(const float4*)(rp + rb2 + (isK?384:0) + c40);
      if (!isK) nV = *(const float4*)(rp + rb2 + 768 + c40);
      if (tid>=480) nB = bp[(long)((c+1)*TCH + brow)*NHEAD];
    }
    float4 g4;
    if (tid<256)
      g4 = *(const float4*)(QKVG + (rowbase + c*TCH + et)*DFF + 1152 + hh*32 + ev0);

    // 32 steps from buf[cur], reg-prefetch t+1
    float4 k4 = *(const float4*)&Kc[cur][0][kq*4];
    float4 q4 = *(const float4*)&Qc[cur][0][kq*4];
    float vt = Vc[cur][0][v];
    float bt = Bc[cur][0];
    #pragma unroll 4
    for (int t=0; t<TCH; ++t){
      int tn = (t+1<TCH)?(t+1):t;
      float4 k4n = *(const float4*)&Kc[cur][tn][kq*4];
      float4 q4n = *(const float4*)&Qc[cur][tn][kq*4];
      float vn = Vc[cur][tn][v];
      float bn = Bc[cur][tn];
      float pa = k4.x*S[0] + k4.y*S[1];
      float pb = k4.z*S[2] + k4.w*S[3];
      float p = red8(pa+pb);
      float err = (vt - p)*bt;
      S[0] = dec*S[0] + k4.x*err;
      S[1] = dec*S[1] + k4.y*err;
      S[2] = dec*S[2] + k4.z*err;
      S[3] = dec*S[3] + k4.w*err;
      float oa = q4.x*S[0] + q4.y*S[1];
      float ob = q4.z*S[2] + q4.w*S[3];
      float o = red8(oa+ob);
      if (kq==0) Ofs[st][t][v] = o;
      k4=k4n; q4=q4n; vt=vn; bt=bn;
    }
    // write staged next chunk (buffer was last read in chunk c-1; safe)
    if (c+1 < SEQ/TCH){
      int nxt = (c+1)&1;
      if (isK) *(float4*)&Kc[nxt][r0][c40] = nA;
      else { *(float4*)&Qc[nxt][r0][c40] = nA; *(float4*)&Vc[nxt][r0][c40] = nV; }
      if (tid>=480) Bc[nxt][brow] = nB;
    }
    __syncthreads();
    // epilogue: mix + gate + bf16 store (256 threads cover 32 rows x 32 v)
    if (tid < 256){
      long r = rowbase + c*TCH + et;
      float4 of = *(const float4*)&Ofs[0][et][ev0];
      float4 os = *(const float4*)&Ofs[1][et][ev0];
      float a0 = (mix*of.x + (1.f-mix)*os.x)*g4.x;
      float a1 = (mix*of.y + (1.f-mix)*os.y)*g4.y;
      float a2 = (mix*of.z + (1.f-mix)*os.z)*g4.z;
      float a3 = (mix*of.w + (1.f-mix)*os.w)*g4.w;
      uint2 o2; o2.x = pk2(a0,a1); o2.y = pk2(a2,a3);
      *(uint2*)(OA + r*DMODEL + hh*32 + ev0) = o2;
    }
    __syncthreads();
  }
}

// ---------------- masked mean pool + L2 normalize ----------------
__global__ __launch_bounds__(384) void pool_norm_kernel(
    const float* __restrict__ h, const int* __restrict__ mask, float* __restrict__ out)
{
  int b = blockIdx.x; int d = threadIdx.x;
  float s=0.f, ms=0.f;
  for (int t=0;t<SEQ;t++){
    float m = (float)mask[b*SEQ+t];
    s += h[((long)b*SEQ+t)*DMODEL + d]*m;
    ms += m;
  }
  float emb = s / fmaxf(ms, 1e-9f);
  float ss = emb*emb;
  #pragma unroll
  for (int m2=1;m2<64;m2<<=1) ss += __shfl_xor(ss,m2);
  __shared__ float r[6];
  if ((d&63)==0) r[d>>6]=ss;
  __syncthreads();
  ss = r[0]+r[1]+r[2]+r[3]+r[4]+r[5];
  out[b*DMODEL+d] = emb / (sqrtf(ss)+1e-12f);
}

extern "C" void kernel_launch(void* const* d_in, const int* in_sizes, int n_in,
                              void* d_out, int out_size, void* d_ws, size_t ws_size,
                              hipStream_t stream)
{
  const int*   ids   = (const int*)d_in[0];
  const int*   amask = (const int*)d_in[1];
  const float* etok  = (const float*)d_in[2];
  const float* epos  = (const float*)d_in[3];
  const float* etyp  = (const float*)d_in[4];
  const float* elng  = (const float*)d_in[5];
  const float* elnb  = (const float*)d_in[6];
  const float* Wq = (const float*)d_in[7];  const float* bq = (const float*)d_in[8];
  const float* Wk = (const float*)d_in[9];  const float* bk = (const float*)d_in[10];
  const float* Wv = (const float*)d_in[11]; const float* bv = (const float*)d_in[12];
  const float* Wb = (const float*)d_in[13]; const float* bb = (const float*)d_in[14];
  const float* dfl = (const float*)d_in[15];
  const float* dsl = (const float*)d_in[16];
  const float* mixl= (const float*)d_in[17];
  const float* Wg = (const float*)d_in[18];
  const float* Wo = (const float*)d_in[19]; const float* bo = (const float*)d_in[20];
  const float* alng = (const float*)d_in[21]; const float* alnb = (const float*)d_in[22];
  const float* W1 = (const float*)d_in[23]; const float* b1 = (const float*)d_in[24];
  const float* W2 = (const float*)d_in[25]; const float* b2 = (const float*)d_in[26];
  const float* flng = (const float*)d_in[27]; const float* flnb = (const float*)d_in[28];

  float* ws = (float*)d_ws;
  const long TD = (long)NTOK*DMODEL;
  float* h    = ws;                            // [8192][384] f32
  ushort* hbf = (ushort*)(h + TD);             // [8192][384] bf16
  float* QKVG = h + TD + TD/2;                 // [8192][1536] f32
  ushort* OA  = (ushort*)(QKVG + 4*TD);        // [8192][384] bf16
  float* Rb   = QKVG + 4*TD + TD/2;            // attn/ffn output f32
  float* Bb   = Rb + TD;                       // [8192][12]
  ushort* WTA = (ushort*)(Bb + (long)NTOK*NHEAD);  // 6 layers x WTAL ushorts
  ushort* F1B = (ushort*)QKVG;                 // FFN mid bf16, aliases dead QKVG

  embed_ln_kernel<<<NTOK,128,0,stream>>>(ids, etok, epos, etyp, elng, elnb, h, hbf);
  tcvt6<<<6*1872,256,0,stream>>>(Wq, Wk, Wv, Wg, Wo, W1, W2, WTA);

  for (int l=0;l<NLAYER;l++){
    ushort* WTAl = WTA + (long)l*WTAL;
    gemm_qkvg<<<dim3(64,12),256,0,stream>>>(hbf, WTAl, bq+l*DMODEL, bk+l*DMODEL, bv+l*DMODEL, QKVG);
    aux_kernel<<<2*NTOK,384,0,stream>>>(QKVG, h, Wb + (long)l*DMODEL*NHEAD, bb + l*NHEAD, amask, Bb);
    scan8_kernel<<<BATCH*NHEAD,512,0,stream>>>(QKVG, Bb, dfl + l*NHEAD, dsl + l*NHEAD, mixl + l*NHEAD, OA);
    gemm_bf2<0,0><<<dim3(64,6),256,0,stream>>>(OA, WTAl+589824, bo + l*DMODEL, Rb, DMODEL, DMODEL);
    add_ln_kernel<<<NTOK,128,0,stream>>>(h, Rb, alng + (long)l*DMODEL, alnb + (long)l*DMODEL, hbf);
    gemm_bf<2,1><<<dim3(64,12),256,0,stream>>>(hbf, WTAl+737280, b1 + (long)l*DFF, F1B, DMODEL, DFF);
    gemm_bf2<0,0><<<dim3(64,6),256,0,stream>>>(F1B, WTAl+1327104, b2 + (long)l*DMODEL, Rb, DFF, DMODEL);
    add_ln_kernel<<<NTOK,128,0,stream>>>(h, Rb, flng + (long)l*DMODEL, flnb + (long)l*DMODEL, hbf);
  }

  pool_norm_kernel<<<BATCH,384,0,stream>>>(h, amask, (float*)d_out);
}

// Round 9
// 1368.696 us; speedup vs baseline: 1.4596x; 1.0343x over previous
//
#include <hip/hip_runtime.h>
#include <hip/hip_bf16.h>

#define NTOK   8192
#define DMODEL 384
#define NHEAD  12
#define DHEAD  32
#define NLAYER 6
#define DFF    1536
#define SEQ    512
#define BATCH  16
#define WTAL   1916928L

typedef __attribute__((ext_vector_type(8))) short short8;
typedef __attribute__((ext_vector_type(4))) float f32x4;

__device__ __forceinline__ float sigmoidf_(float x){ return 1.f/(1.f+expf(-x)); }

__device__ __forceinline__ ushort f2b(float x){
  uint b = __builtin_bit_cast(uint, x);
  uint r = (b + 0x7FFFu + ((b>>16)&1u)) >> 16;
  return (ushort)r;
}
__device__ __forceinline__ uint pk2(float lo, float hi){
  return (uint)f2b(lo) | ((uint)f2b(hi)<<16);
}
// 8-lane sum within any aligned 8-lane group: quad xor1, quad xor2, row_half_mirror
__device__ __forceinline__ float red8(float x){
  int t = __builtin_amdgcn_update_dpp(0, __builtin_bit_cast(int,x), 0xB1, 0xF, 0xF, true);
  x += __builtin_bit_cast(float,t);
  t = __builtin_amdgcn_update_dpp(0, __builtin_bit_cast(int,x), 0x4E, 0xF, 0xF, true);
  x += __builtin_bit_cast(float,t);
  t = __builtin_amdgcn_update_dpp(0, __builtin_bit_cast(int,x), 0x141, 0xF, 0xF, true);
  x += __builtin_bit_cast(float,t);
  return x;
}
__device__ __forceinline__ void gload16(const ushort* g, ushort* l){
  __builtin_amdgcn_global_load_lds((const __attribute__((address_space(1))) void*)g,
                                   (__attribute__((address_space(3))) void*)l, 16, 0, 0);
}

// ---------------- embedding + LN (f32 + bf16 shadow) ----------------
__global__ __launch_bounds__(128) void embed_ln_kernel(
    const int* __restrict__ ids, const float* __restrict__ tok,
    const float* __restrict__ pos, const float* __restrict__ typ,
    const float* __restrict__ g, const float* __restrict__ bvec,
    float* __restrict__ out, ushort* __restrict__ outb)
{
  int n = blockIdx.x;
  int t = n & (SEQ-1);
  int id = ids[n];
  int tid = threadIdx.x;
  float v[3]; float s1=0.f, s2=0.f;
  #pragma unroll
  for (int j=0;j<3;j++){
    int d = tid + j*128;
    float x = tok[(long)id*DMODEL + d] + pos[t*DMODEL + d] + typ[d];
    v[j]=x; s1+=x; s2+=x*x;
  }
  #pragma unroll
  for (int m=1;m<64;m<<=1){ s1 += __shfl_xor(s1,m); s2 += __shfl_xor(s2,m); }
  __shared__ float r1[2], r2[2];
  if ((tid&63)==0){ r1[tid>>6]=s1; r2[tid>>6]=s2; }
  __syncthreads();
  s1 = r1[0]+r1[1]; s2 = r2[0]+r2[1];
  float mean = s1*(1.f/DMODEL);
  float var  = s2*(1.f/DMODEL) - mean*mean;
  float inv  = rsqrtf(var + 1e-12f);
  #pragma unroll
  for (int j=0;j<3;j++){
    int d = tid + j*128;
    float y = (v[j]-mean)*inv*g[d] + bvec[d];
    out[(long)n*DMODEL + d] = y;
    outb[(long)n*DMODEL + d] = f2b(y);
  }
}

// ---------------- residual add + LN (f32 + bf16 shadow) ----------------
__global__ __launch_bounds__(128) void add_ln_kernel(
    float* __restrict__ h, const float* __restrict__ res,
    const float* __restrict__ g, const float* __restrict__ bvec,
    ushort* __restrict__ hb)
{
  int n = blockIdx.x;
  int tid = threadIdx.x;
  float v[3]; float s1=0.f, s2=0.f;
  #pragma unroll
  for (int j=0;j<3;j++){
    int d = tid + j*128;
    float x = h[(long)n*DMODEL + d] + res[(long)n*DMODEL + d];
    v[j]=x; s1+=x; s2+=x*x;
  }
  #pragma unroll
  for (int m=1;m<64;m<<=1){ s1 += __shfl_xor(s1,m); s2 += __shfl_xor(s2,m); }
  __shared__ float r1[2], r2[2];
  if ((tid&63)==0){ r1[tid>>6]=s1; r2[tid>>6]=s2; }
  __syncthreads();
  s1 = r1[0]+r1[1]; s2 = r2[0]+r2[1];
  float mean = s1*(1.f/DMODEL);
  float var  = s2*(1.f/DMODEL) - mean*mean;
  float inv  = rsqrtf(var + 1e-12f);
  #pragma unroll
  for (int j=0;j<3;j++){
    int d = tid + j*128;
    float y = (v[j]-mean)*inv*g[d] + bvec[d];
    h[(long)n*DMODEL + d] = y;
    hb[(long)n*DMODEL + d] = f2b(y);
  }
}

// ---------------- ALL-layer weight transpose+convert (runs once) ----------------
__global__ __launch_bounds__(256) void tcvt6(
    const float* __restrict__ Wq, const float* __restrict__ Wk,
    const float* __restrict__ Wv, const float* __restrict__ Wg,
    const float* __restrict__ Wo, const float* __restrict__ W1,
    const float* __restrict__ W2, ushort* __restrict__ WTA)
{
  __shared__ float tile[32][33];
  int l = blockIdx.x / 1872;
  int bid = blockIdx.x % 1872;
  const float* Wq_l = Wq + (long)l*DMODEL*DMODEL;
  const float* Wk_l = Wk + (long)l*DMODEL*DMODEL;
  const float* Wv_l = Wv + (long)l*DMODEL*DMODEL;
  const float* Wg_l = Wg + (long)l*DMODEL*DMODEL;
  const float* Wo_l = Wo + (long)l*DMODEL*DMODEL;
  const float* W1_l = W1 + (long)l*DMODEL*DFF;
  const float* W2_l = W2 + (long)l*DFF*DMODEL;
  ushort* WTAl = WTA + (long)l*WTAL;

  const float* src; long dstbase; int rowlen, Nd, tk, tn, row0;
  if (bid < 720){
    int seg = bid/144, t = bid%144;
    tk = t%12; tn = t/12;
    src = (seg==0)?Wq_l:(seg==1)?Wk_l:(seg==2)?Wv_l:(seg==3)?Wg_l:Wo_l;
    Nd = 384; rowlen = 384;
    if (seg<4){ dstbase=0; row0=seg*384; }
    else      { dstbase=589824; row0=0; }
  } else if (bid < 1296){
    int t = bid-720; tk=t%12; tn=t/12;
    src=W1_l; Nd=DFF; dstbase=737280; row0=0; rowlen=384;
  } else {
    int t = bid-1296; tk=t%48; tn=t/48;
    src=W2_l; Nd=384; dstbase=1327104; row0=0; rowlen=DFF;
  }
  int k0=tk*32, n0=tn*32;
  int tt=threadIdx.x;
  int r=tt>>3, c4=(tt&7)<<2;
  const float* sp = src + (long)(k0+r)*Nd + n0 + c4;
  float4 f = *(const float4*)sp;
  tile[r][c4+0]=f.x; tile[r][c4+1]=f.y; tile[r][c4+2]=f.z; tile[r][c4+3]=f.w;
  __syncthreads();
  ushort4 o;
  o.x=f2b(tile[c4+0][r]); o.y=f2b(tile[c4+1][r]);
  o.z=f2b(tile[c4+2][r]); o.w=f2b(tile[c4+3][r]);
  *(ushort4*)(WTAl + dstbase + (long)(row0+n0+r)*rowlen + k0 + c4) = o;
}

// XCD-aware swizzle: grid (64, ny), total %8==0. Returns (bx,by).
__device__ __forceinline__ int2 xcd_swz(){
  int lin = blockIdx.y*64 + blockIdx.x;
  int nb = gridDim.x*gridDim.y;
  int s = (lin & 7)*(nb>>3) + (lin>>3);
  return make_int2(s & 63, s >> 6);
}

// ---------------- bf16 MFMA GEMM, 128x128 tile ----------------
template<int ACT, int OUTBF>
__global__ __launch_bounds__(256) void gemm_bf(
    const ushort* __restrict__ Xb, const ushort* __restrict__ WT,
    const float* __restrict__ bias, void* __restrict__ Cv, int Kd, int Nd)
{
  __shared__ ushort A_lds[128*32];
  __shared__ ushort B_lds[128*32];
  int tid = threadIdx.x;
  int2 bxy = xcd_swz();
  int bm = bxy.x*128, bn = bxy.y*128;
  int w = tid>>6, lane = tid&63;
  int wm = w>>1, wn = w&1;
  f32x4 acc[4][4];
  #pragma unroll
  for (int i=0;i<4;i++)
    #pragma unroll
    for (int j=0;j<4;j++) acc[i][j]=(f32x4)(0.f);

  int cl = lane&15, koff = (lane>>4)*8;
  int srow = w*32 + (lane>>2);
  int scol = (lane&3)*8;
  const ushort* gA0 = Xb + (long)(bm+srow)*Kd + scol;
  const ushort* gA1 = gA0 + 16*(long)Kd;
  const ushort* gB0 = WT + (long)(bn+srow)*Kd + scol;
  const ushort* gB1 = gB0 + 16*(long)Kd;
  ushort* lA = A_lds + w*1024;
  ushort* lB = B_lds + w*1024;

  for (int k0=0; k0<Kd; k0+=32){
    gload16(gA0+k0, lA);
    gload16(gA1+k0, lA+512);
    gload16(gB0+k0, lB);
    gload16(gB1+k0, lB+512);
    __syncthreads();
    short8 bf[4];
    #pragma unroll
    for (int ni=0;ni<4;ni++)
      bf[ni] = *(const short8*)&B_lds[(wn*64+ni*16+cl)*32 + koff];
    #pragma unroll
    for (int mi=0;mi<4;mi++){
      short8 af = *(const short8*)&A_lds[(wm*64+mi*16+cl)*32 + koff];
      #pragma unroll
      for (int ni=0;ni<4;ni++)
        acc[mi][ni] = __builtin_amdgcn_mfma_f32_16x16x32_bf16(af, bf[ni], acc[mi][ni], 0,0,0);
    }
    __syncthreads();
  }

  int rb = (lane>>4)*4;
  #pragma unroll
  for (int ni=0; ni<4; ni++){
    int col = bn + wn*64 + ni*16 + cl;
    float bsv = bias ? bias[col] : 0.f;
    #pragma unroll
    for (int mi=0; mi<4; mi++){
      #pragma unroll
      for (int j=0;j<4;j++){
        int row = bm + wm*64 + mi*16 + rb + j;
        float c = acc[mi][ni][j] + bsv;
        if (ACT==1)      c = c*sigmoidf_(c);
        else if (ACT==2) c = 0.5f*c*(1.f+erff(c*0.70710678118f));
        else if (ACT==3) c = sigmoidf_(c);
        if (OUTBF) ((ushort*)Cv)[(long)row*Nd + col] = f2b(c);
        else       ((float*)Cv)[(long)row*Nd + col] = c;
      }
    }
  }
}

// ---------------- bf16 MFMA GEMM, 128x64 tile ----------------
template<int ACT, int OUTBF>
__global__ __launch_bounds__(256) void gemm_bf2(
    const ushort* __restrict__ Xb, const ushort* __restrict__ WT,
    const float* __restrict__ bias, void* __restrict__ Cv, int Kd, int Nd)
{
  __shared__ ushort A_lds[128*32];
  __shared__ ushort B_lds[64*32];
  int tid = threadIdx.x;
  int2 bxy = xcd_swz();
  int bm = bxy.x*128, bn = bxy.y*64;
  int w = tid>>6, lane = tid&63;
  int wm = w>>1, wn = w&1;
  f32x4 acc[4][2];
  #pragma unroll
  for (int i=0;i<4;i++){ acc[i][0]=(f32x4)(0.f); acc[i][1]=(f32x4)(0.f); }

  int cl = lane&15, koff = (lane>>4)*8;
  int srowA = w*32 + (lane>>2);
  int scol = (lane&3)*8;
  const ushort* gA0 = Xb + (long)(bm+srowA)*Kd + scol;
  const ushort* gA1 = gA0 + 16*(long)Kd;
  int srowB = w*16 + (lane>>2);
  const ushort* gB = WT + (long)(bn+srowB)*Kd + scol;
  ushort* lA = A_lds + w*1024;
  ushort* lB = B_lds + w*512;

  for (int k0=0; k0<Kd; k0+=32){
    gload16(gA0+k0, lA);
    gload16(gA1+k0, lA+512);
    gload16(gB+k0, lB);
    __syncthreads();
    short8 b0 = *(const short8*)&B_lds[(wn*32+cl)*32 + koff];
    short8 b1 = *(const short8*)&B_lds[(wn*32+16+cl)*32 + koff];
    #pragma unroll
    for (int mi=0;mi<4;mi++){
      short8 af = *(const short8*)&A_lds[(wm*64+mi*16+cl)*32 + koff];
      acc[mi][0] = __builtin_amdgcn_mfma_f32_16x16x32_bf16(af, b0, acc[mi][0], 0,0,0);
      acc[mi][1] = __builtin_amdgcn_mfma_f32_16x16x32_bf16(af, b1, acc[mi][1], 0,0,0);
    }
    __syncthreads();
  }

  int rb = (lane>>4)*4;
  #pragma unroll
  for (int ni=0; ni<2; ni++){
    int col = bn + wn*32 + ni*16 + cl;
    float bsv = bias ? bias[col] : 0.f;
    #pragma unroll
    for (int mi=0; mi<4; mi++){
      #pragma unroll
      for (int j=0;j<4;j++){
        int row = bm + wm*64 + mi*16 + rb + j;
        float c = acc[mi][ni][j] + bsv;
        if (ACT==1)      c = c*sigmoidf_(c);
        else if (ACT==2) c = 0.5f*c*(1.f+erff(c*0.70710678118f));
        else if (ACT==3) c = sigmoidf_(c);
        if (OUTBF) ((ushort*)Cv)[(long)row*Nd + col] = f2b(c);
        else       ((float*)Cv)[(long)row*Nd + col] = c;
      }
    }
  }
}

// ---------------- fused QKVG GEMM (f32 out, per-segment act/bias) ----------------
__global__ __launch_bounds__(256) void gemm_qkvg(
    const ushort* __restrict__ Xb, const ushort* __restrict__ WT,
    const float* __restrict__ bq, const float* __restrict__ bk,
    const float* __restrict__ bv, float* __restrict__ C)
{
  __shared__ ushort A_lds[128*32];
  __shared__ ushort B_lds[128*32];
  int tid = threadIdx.x;
  int2 bxy = xcd_swz();
  int bm = bxy.x*128, bn = bxy.y*128;
  int w = tid>>6, lane = tid&63;
  int wm = w>>1, wn = w&1;
  f32x4 acc[4][4];
  #pragma unroll
  for (int i=0;i<4;i++)
    #pragma unroll
    for (int j=0;j<4;j++) acc[i][j]=(f32x4)(0.f);

  int cl = lane&15, koff = (lane>>4)*8;
  int srow = w*32 + (lane>>2);
  int scol = (lane&3)*8;
  const ushort* gA0 = Xb + (long)(bm+srow)*DMODEL + scol;
  const ushort* gA1 = gA0 + 16*DMODEL;
  const ushort* gB0 = WT + (long)(bn+srow)*DMODEL + scol;
  const ushort* gB1 = gB0 + 16*DMODEL;
  ushort* lA = A_lds + w*1024;
  ushort* lB = B_lds + w*1024;

  for (int k0=0; k0<DMODEL; k0+=32){
    gload16(gA0+k0, lA);
    gload16(gA1+k0, lA+512);
    gload16(gB0+k0, lB);
    gload16(gB1+k0, lB+512);
    __syncthreads();
    short8 bf[4];
    #pragma unroll
    for (int ni=0;ni<4;ni++)
      bf[ni] = *(const short8*)&B_lds[(wn*64+ni*16+cl)*32 + koff];
    #pragma unroll
    for (int mi=0;mi<4;mi++){
      short8 af = *(const short8*)&A_lds[(wm*64+mi*16+cl)*32 + koff];
      #pragma unroll
      for (int ni=0;ni<4;ni++)
        acc[mi][ni] = __builtin_amdgcn_mfma_f32_16x16x32_bf16(af, bf[ni], acc[mi][ni], 0,0,0);
    }
    __syncthreads();
  }

  int seg = bxy.y/3;
  const float* bp = (seg==0)?bq:(seg==1)?bk:(seg==2)?bv:nullptr;
  int boff = seg*384;
  int rb = (lane>>4)*4;
  #pragma unroll
  for (int ni=0; ni<4; ni++){
    int col = bn + wn*64 + ni*16 + cl;
    float bsv = bp ? bp[col-boff] : 0.f;
    #pragma unroll
    for (int mi=0; mi<4; mi++){
      #pragma unroll
      for (int j=0;j<4;j++){
        int row = bm + wm*64 + mi*16 + rb + j;
        float c = acc[mi][ni][j] + bsv;
        if (seg<2)       c = c*sigmoidf_(c);
        else if (seg==3) c = sigmoidf_(c);
        C[(long)row*DFF + col] = c;
      }
    }
  }
}

// ---------------- beta = sigmoid(x @ Wb + bb) * mask ----------------
__global__ __launch_bounds__(384) void beta_kernel(
    const float* __restrict__ X, const float* __restrict__ Wb, const float* __restrict__ bb,
    const int* __restrict__ mask, float* __restrict__ Bb)
{
  __shared__ float xs[DMODEL];
  int n = blockIdx.x; int tid = threadIdx.x;
  xs[tid] = X[(long)n*DMODEL + tid];
  __syncthreads();
  int hh = tid >> 5, i = tid & 31;
  float s = 0.f;
  for (int d=i; d<DMODEL; d+=32) s += xs[d]*Wb[d*NHEAD+hh];
  #pragma unroll
  for (int m=1;m<32;m<<=1) s += __shfl_xor(s,m);
  if (i==0) Bb[n*NHEAD+hh] = (float)mask[n] * sigmoidf_(s + bb[hh]);
}

// ---------------- delta-rule scan v9 ----------------
// 192 blocks = (b,h); 512 thr = 8 waves: st = w>>2, vq = w&3.
// lane: kq = lane&7 (k = kq*4..+3), v = vq*8 + (lane>>3). S[4] in regs.
// TCH=64, single LDS buffer + reg-staged next chunk (T14). knorm fused into staging
// (free red8 on values in regs). V transposed [v][t] -> b128 per 4 steps. B via
// float4 broadcast per 4 steps. Row 64 = pad for unconditional t+1 prefetch.
__global__ __launch_bounds__(512,2) void scan9_kernel(
    const float* __restrict__ QKVG, const float* __restrict__ Bb,
    const float* __restrict__ dfl, const float* __restrict__ dsl,
    const float* __restrict__ mixl, ushort* __restrict__ OA)
{
  __shared__ float Qc[65][36], Kc[65][36], Vt[32][68], Bc[64], Ofs[2][64][36];
  int bh = blockIdx.x;
  int b = bh / NHEAD, hh = bh - b*NHEAD;
  int tid = threadIdx.x;
  int w = tid>>6, lane = tid&63;
  int st = w>>2, vq = w&3;
  int kq = lane&7, v = vq*8 + (lane>>3);
  float dec = sigmoidf_(st ? dsl[hh] : dfl[hh]);
  float mix = sigmoidf_(mixl[hh]);
  long rowbase = (long)b*SEQ;
  const float* rp = QKVG + rowbase*DFF + hh*32;
  const float* bp = Bb + rowbase*NHEAD + hh;

  int r0 = tid>>3, c40 = (tid&7)<<2;     // staging/epilogue: 64 rows x 8 col-groups
  float S[4] = {0.f,0.f,0.f,0.f};

  // ---- stage chunk 0 (knorm fused: 8 staging lanes of a row form one red8 group)
  float4 sq, sk, sv; float sb = 0.f;
  {
    long g = (long)r0*DFF;
    sq = *(const float4*)(rp + g + c40);
    sk = *(const float4*)(rp + g + 384 + c40);
    sv = *(const float4*)(rp + g + 768 + c40);
    if (tid < 64) sb = bp[(long)tid*NHEAD];
    float ss = red8(sk.x*sk.x + sk.y*sk.y + sk.z*sk.z + sk.w*sk.w);
    float inv = 1.f/(sqrtf(ss)+1e-6f);
    sk.x*=inv; sk.y*=inv; sk.z*=inv; sk.w*=inv;
    *(float4*)&Qc[r0][c40] = sq;
    *(float4*)&Kc[r0][c40] = sk;
    Vt[c40+0][r0]=sv.x; Vt[c40+1][r0]=sv.y; Vt[c40+2][r0]=sv.z; Vt[c40+3][r0]=sv.w;
    if (tid < 64) Bc[tid] = sb;
  }
  __syncthreads();

  for (int c=0; c<8; ++c){
    // issue next-chunk global loads (consumed after the 64-step compute)
    if (c < 7){
      long g = (long)((c+1)*64 + r0)*DFF;
      sq = *(const float4*)(rp + g + c40);
      sk = *(const float4*)(rp + g + 384 + c40);
      sv = *(const float4*)(rp + g + 768 + c40);
      if (tid < 64) sb = bp[(long)((c+1)*64 + tid)*NHEAD];
    }
    float4 g4 = *(const float4*)(rp + (long)(c*64 + r0)*DFF + 1152 + c40);

    // ---- 64 steps
    float4 k4 = *(const float4*)&Kc[0][kq*4];
    float4 q4 = *(const float4*)&Qc[0][kq*4];
    for (int t4=0; t4<16; ++t4){
      float br[4]; *(float4*)br = *(const float4*)&Bc[t4*4];
      float vr[4]; *(float4*)vr = *(const float4*)&Vt[v][t4*4];
      #pragma unroll
      for (int i=0;i<4;i++){
        int t = t4*4 + i;
        float4 k4n = *(const float4*)&Kc[t+1][kq*4];   // row 64 = pad, unused
        float4 q4n = *(const float4*)&Qc[t+1][kq*4];
        float pa = k4.x*S[0] + k4.y*S[1];
        float pb = k4.z*S[2] + k4.w*S[3];
        float p = red8(pa+pb);
        float err = (vr[i] - p)*br[i];
        S[0] = dec*S[0] + k4.x*err;
        S[1] = dec*S[1] + k4.y*err;
        S[2] = dec*S[2] + k4.z*err;
        S[3] = dec*S[3] + k4.w*err;
        float oa = q4.x*S[0] + q4.y*S[1];
        float ob = q4.z*S[2] + q4.w*S[3];
        float o = red8(oa+ob);
        if (kq==0) Ofs[st][t][v] = o;
        k4=k4n; q4=q4n;
      }
    }
    __syncthreads();

    // ---- epilogue (mix+gate+bf16 out) + write staged next chunk
    {
      float4 of = *(const float4*)&Ofs[0][r0][c40];
      float4 os = *(const float4*)&Ofs[1][r0][c40];
      float a0 = (mix*of.x + (1.f-mix)*os.x)*g4.x;
      float a1 = (mix*of.y + (1.f-mix)*os.y)*g4.y;
      float a2 = (mix*of.z + (1.f-mix)*os.z)*g4.z;
      float a3 = (mix*of.w + (1.f-mix)*os.w)*g4.w;
      uint2 o2; o2.x = pk2(a0,a1); o2.y = pk2(a2,a3);
      *(uint2*)(OA + (rowbase + c*64 + r0)*DMODEL + hh*32 + c40) = o2;
    }
    if (c < 7){
      float ss = red8(sk.x*sk.x + sk.y*sk.y + sk.z*sk.z + sk.w*sk.w);
      float inv = 1.f/(sqrtf(ss)+1e-6f);
      sk.x*=inv; sk.y*=inv; sk.z*=inv; sk.w*=inv;
      *(float4*)&Qc[r0][c40] = sq;
      *(float4*)&Kc[r0][c40] = sk;
      Vt[c40+0][r0]=sv.x; Vt[c40+1][r0]=sv.y; Vt[c40+2][r0]=sv.z; Vt[c40+3][r0]=sv.w;
      if (tid < 64) Bc[tid] = sb;
    }
    __syncthreads();
  }
}

// ---------------- masked mean pool + L2 normalize ----------------
__global__ __launch_bounds__(384) void pool_norm_kernel(
    const float* __restrict__ h, const int* __restrict__ mask, float* __restrict__ out)
{
  int b = blockIdx.x; int d = threadIdx.x;
  float s=0.f, ms=0.f;
  for (int t=0;t<SEQ;t++){
    float m = (float)mask[b*SEQ+t];
    s += h[((long)b*SEQ+t)*DMODEL + d]*m;
    ms += m;
  }
  float emb = s / fmaxf(ms, 1e-9f);
  float ss = emb*emb;
  #pragma unroll
  for (int m2=1;m2<64;m2<<=1) ss += __shfl_xor(ss,m2);
  __shared__ float r[6];
  if ((d&63)==0) r[d>>6]=ss;
  __syncthreads();
  ss = r[0]+r[1]+r[2]+r[3]+r[4]+r[5];
  out[b*DMODEL+d] = emb / (sqrtf(ss)+1e-12f);
}

extern "C" void kernel_launch(void* const* d_in, const int* in_sizes, int n_in,
                              void* d_out, int out_size, void* d_ws, size_t ws_size,
                              hipStream_t stream)
{
  const int*   ids   = (const int*)d_in[0];
  const int*   amask = (const int*)d_in[1];
  const float* etok  = (const float*)d_in[2];
  const float* epos  = (const float*)d_in[3];
  const float* etyp  = (const float*)d_in[4];
  const float* elng  = (const float*)d_in[5];
  const float* elnb  = (const float*)d_in[6];
  const float* Wq = (const float*)d_in[7];  const float* bq = (const float*)d_in[8];
  const float* Wk = (const float*)d_in[9];  const float* bk = (const float*)d_in[10];
  const float* Wv = (const float*)d_in[11]; const float* bv = (const float*)d_in[12];
  const float* Wb = (const float*)d_in[13]; const float* bb = (const float*)d_in[14];
  const float* dfl = (const float*)d_in[15];
  const float* dsl = (const float*)d_in[16];
  const float* mixl= (const float*)d_in[17];
  const float* Wg = (const float*)d_in[18];
  const float* Wo = (const float*)d_in[19]; const float* bo = (const float*)d_in[20];
  const float* alng = (const float*)d_in[21]; const float* alnb = (const float*)d_in[22];
  const float* W1 = (const float*)d_in[23]; const float* b1 = (const float*)d_in[24];
  const float* W2 = (const float*)d_in[25]; const float* b2 = (const float*)d_in[26];
  const float* flng = (const float*)d_in[27]; const float* flnb = (const float*)d_in[28];

  float* ws = (float*)d_ws;
  const long TD = (long)NTOK*DMODEL;
  float* h    = ws;                            // [8192][384] f32
  ushort* hbf = (ushort*)(h + TD);             // [8192][384] bf16
  float* QKVG = h + TD + TD/2;                 // [8192][1536] f32
  ushort* OA  = (ushort*)(QKVG + 4*TD);        // [8192][384] bf16
  float* Rb   = QKVG + 4*TD + TD/2;            // attn/ffn output f32
  float* Bb   = Rb + TD;                       // [8192][12]
  ushort* WTA = (ushort*)(Bb + (long)NTOK*NHEAD);  // 6 layers x WTAL ushorts
  ushort* F1B = (ushort*)QKVG;                 // FFN mid bf16, aliases dead QKVG

  embed_ln_kernel<<<NTOK,128,0,stream>>>(ids, etok, epos, etyp, elng, elnb, h, hbf);
  tcvt6<<<6*1872,256,0,stream>>>(Wq, Wk, Wv, Wg, Wo, W1, W2, WTA);

  for (int l=0;l<NLAYER;l++){
    ushort* WTAl = WTA + (long)l*WTAL;
    gemm_qkvg<<<dim3(64,12),256,0,stream>>>(hbf, WTAl, bq+l*DMODEL, bk+l*DMODEL, bv+l*DMODEL, QKVG);
    beta_kernel<<<NTOK,384,0,stream>>>(h, Wb + (long)l*DMODEL*NHEAD, bb + l*NHEAD, amask, Bb);
    scan9_kernel<<<BATCH*NHEAD,512,0,stream>>>(QKVG, Bb, dfl + l*NHEAD, dsl + l*NHEAD, mixl + l*NHEAD, OA);
    gemm_bf2<0,0><<<dim3(64,6),256,0,stream>>>(OA, WTAl+589824, bo + l*DMODEL, Rb, DMODEL, DMODEL);
    add_ln_kernel<<<NTOK,128,0,stream>>>(h, Rb, alng + (long)l*DMODEL, alnb + (long)l*DMODEL, hbf);
    gemm_bf<2,1><<<dim3(64,12),256,0,stream>>>(hbf, WTAl+737280, b1 + (long)l*DFF, F1B, DMODEL, DFF);
    gemm_bf2<0,0><<<dim3(64,6),256,0,stream>>>(F1B, WTAl+1327104, b2 + (long)l*DMODEL, Rb, DFF, DMODEL);
    add_ln_kernel<<<NTOK,128,0,stream>>>(h, Rb, flng + (long)l*DMODEL, flnb + (long)l*DMODEL, hbf);
  }

  pool_norm_kernel<<<BATCH,384,0,stream>>>(h, amask, (float*)d_out);
}